// Round 11
// baseline (335.075 us; speedup 1.0000x reference)
//
#include <hip/hip_runtime.h>

#define N_NODES 100000
#define N_EDGES 1600000
#define TOT (N_EDGES + N_NODES)
#define IN_CH 256
#define NHEAD 4
#define CH 64
#define HC 256
#define NEG_SLOPE 0.2f

typedef _Float16 half8 __attribute__((ext_vector_type(8)));
typedef _Float16 h2v __attribute__((ext_vector_type(2)));
typedef float f32x4 __attribute__((ext_vector_type(4)));
typedef unsigned short ushort_t;
typedef unsigned int uint_t;

static __device__ __forceinline__ ushort_t f2h(float f) {
  _Float16 h = (_Float16)f;
  return __builtin_bit_cast(ushort_t, h);
}

// ---------------- W fp32 [K=256][N=256] -> Wt_arr, MFMA-fragment-major ----------------
// uint4 index f = (ks*16 + n)*64 + lane ; halfs j=0..7 :
//   W[ ks*32 + (lane>>4)*8 + j ][ n*16 + (lane&15) ]
__global__ __launch_bounds__(256) void conv_w(const float* __restrict__ W,
                                              uint4* __restrict__ Wt_arr) {
  int id = blockIdx.x * 256 + threadIdx.x;  // 0..8191
  int lane = id & 63;
  int n = (id >> 6) & 15;
  int ks = id >> 10;
  int col = n * 16 + (lane & 15);
  int kbase = ks * 32 + (lane >> 4) * 8;
  ushort_t h[8];
#pragma unroll
  for (int j = 0; j < 8; ++j) h[j] = f2h(W[(size_t)(kbase + j) * HC + col]);
  uint4 u;
  u.x = (uint_t)h[0] | ((uint_t)h[1] << 16);
  u.y = (uint_t)h[2] | ((uint_t)h[3] << 16);
  u.z = (uint_t)h[4] | ((uint_t)h[5] << 16);
  u.w = (uint_t)h[6] | ((uint_t)h[7] << 16);
  Wt_arr[id] = u;
}

// ---------------- barrier-free LDS-free MFMA GEMM + fused attn dots ------------------
// 256 threads = 4 waves; block = 64 rows; wave = 16 rows x 256 cols.
// A: whole K=256 in registers. B: global fragment-major stream, depth-1 prefetch.
__global__ __launch_bounds__(256) void gemm_mfma(const float* __restrict__ X,
                                                 const uint4* __restrict__ Wt_arr,
                                                 const float* __restrict__ att_src,
                                                 const float* __restrict__ att_dst,
                                                 uint2* __restrict__ Hmp,
                                                 float* __restrict__ as_out,
                                                 float* __restrict__ ad_out, int M) {
  const int tid = threadIdx.x;
  const int lane = tid & 63;
  const int wid = tid >> 6;
  const int l16 = lane & 15;
  const int lhi = lane >> 4;
  const int row0 = blockIdx.x * 64;

  int rowA = row0 + wid * 16 + l16;
  if (rowA >= M) rowA = M - 1;  // clamp; stores are guarded
  const float* __restrict__ xr = X + (size_t)rowA * IN_CH + lhi * 8;

  // ---- load ALL A fragments (16 independent dwordx4 in flight), convert to fp16 ----
  half8 afrag[8];
#pragma unroll
  for (int ks = 0; ks < 8; ++ks) {
    float4 xa = *reinterpret_cast<const float4*>(xr + ks * 32);
    float4 xb = *reinterpret_cast<const float4*>(xr + ks * 32 + 4);
    uint4 ua;
    ua.x = __builtin_bit_cast(uint_t, __builtin_amdgcn_cvt_pkrtz(xa.x, xa.y));
    ua.y = __builtin_bit_cast(uint_t, __builtin_amdgcn_cvt_pkrtz(xa.z, xa.w));
    ua.z = __builtin_bit_cast(uint_t, __builtin_amdgcn_cvt_pkrtz(xb.x, xb.y));
    ua.w = __builtin_bit_cast(uint_t, __builtin_amdgcn_cvt_pkrtz(xb.z, xb.w));
    afrag[ks] = __builtin_bit_cast(half8, ua);
  }

  f32x4 acc[16] = {};
  const uint4* __restrict__ wb = Wt_arr + lane;  // + (ks*16+n)*64

  // ---- K loop: depth-1 pipelined B groups (next 4 loads issued before current MFMAs)
  uint4 bn0 = wb[0 * 64], bn1 = wb[1 * 64], bn2 = wb[2 * 64], bn3 = wb[3 * 64];
#pragma unroll
  for (int f = 0; f < 32; ++f) {
    uint4 b0 = bn0, b1 = bn1, b2 = bn2, b3 = bn3;
    if (f < 31) {
      bn0 = wb[((f + 1) * 4 + 0) * 64];
      bn1 = wb[((f + 1) * 4 + 1) * 64];
      bn2 = wb[((f + 1) * 4 + 2) * 64];
      bn3 = wb[((f + 1) * 4 + 3) * 64];
    }
    const int ks = f >> 2;
    const int g = f & 3;
    acc[g * 4 + 0] = __builtin_amdgcn_mfma_f32_16x16x32_f16(
        afrag[ks], __builtin_bit_cast(half8, b0), acc[g * 4 + 0], 0, 0, 0);
    acc[g * 4 + 1] = __builtin_amdgcn_mfma_f32_16x16x32_f16(
        afrag[ks], __builtin_bit_cast(half8, b1), acc[g * 4 + 1], 0, 0, 0);
    acc[g * 4 + 2] = __builtin_amdgcn_mfma_f32_16x16x32_f16(
        afrag[ks], __builtin_bit_cast(half8, b2), acc[g * 4 + 2], 0, 0, 0);
    acc[g * 4 + 3] = __builtin_amdgcn_mfma_f32_16x16x32_f16(
        afrag[ks], __builtin_bit_cast(half8, b3), acc[g * 4 + 3], 0, 0, 0);
  }

  // ---- epilogue: pack Hmp + fused attention dots ----
  float attS[16], attD[16];
#pragma unroll
  for (int n = 0; n < 16; ++n) {
    attS[n] = att_src[n * 16 + l16];
    attD[n] = att_dst[n * 16 + l16];
  }

#pragma unroll
  for (int r = 0; r < 4; ++r) {
    int grow = row0 + wid * 16 + lhi * 4 + r;
    if (grow < M) {
#pragma unroll
      for (int n2 = 0; n2 < 4; ++n2) {
        uint_t pk01 = __builtin_bit_cast(uint_t,
            __builtin_amdgcn_cvt_pkrtz(acc[n2][r], acc[n2 + 4][r]));
        uint_t pk23 = __builtin_bit_cast(uint_t,
            __builtin_amdgcn_cvt_pkrtz(acc[n2 + 8][r], acc[n2 + 12][r]));
        Hmp[(size_t)grow * 64 + n2 * 16 + l16] = make_uint2(pk01, pk23);
      }
      float sv[4] = {0.f, 0.f, 0.f, 0.f}, dv[4] = {0.f, 0.f, 0.f, 0.f};
#pragma unroll
      for (int h = 0; h < 4; ++h)
#pragma unroll
        for (int j = 0; j < 4; ++j) {
          sv[h] += acc[h * 4 + j][r] * attS[h * 4 + j];
          dv[h] += acc[h * 4 + j][r] * attD[h * 4 + j];
        }
#pragma unroll
      for (int off = 1; off < 16; off <<= 1)
#pragma unroll
        for (int h = 0; h < 4; ++h) {
          sv[h] += __shfl_xor(sv[h], off, 16);
          dv[h] += __shfl_xor(dv[h], off, 16);
        }
      if (l16 == 0) {
#pragma unroll
        for (int h = 0; h < 4; ++h) {
          as_out[(size_t)grow * 4 + h] = sv[h];
          ad_out[(size_t)grow * 4 + h] = dv[h];
        }
      }
    }
  }
}

// ---------------- CSR build ----------------
// standalone, vectorized: 1 int4 per thread over real edges
__global__ __launch_bounds__(256) void count_deg(const int* __restrict__ edst,
                                                 int* __restrict__ deg) {
  int t = blockIdx.x * 256 + threadIdx.x;
  if (t >= N_EDGES / 4) return;
  int4 d4 = reinterpret_cast<const int4*>(edst)[t];
  atomicAdd(&deg[d4.x], 1);
  atomicAdd(&deg[d4.y], 1);
  atomicAdd(&deg[d4.z], 1);
  atomicAdd(&deg[d4.w], 1);
}

// scan1 adds the +1 self-loop per node inline.
__global__ __launch_bounds__(256) void scan1(const int* __restrict__ deg,
                                             int* __restrict__ rp,
                                             int* __restrict__ bsum) {
  __shared__ int sh[256];
  int t = threadIdx.x;
  int base = blockIdx.x * 1024 + t * 4;
  int v[4];
#pragma unroll
  for (int i = 0; i < 4; ++i) v[i] = (base + i < N_NODES) ? (deg[base + i] + 1) : 0;
  int tsum = v[0] + v[1] + v[2] + v[3];
  sh[t] = tsum;
  __syncthreads();
  for (int off = 1; off < 256; off <<= 1) {
    int x = (t >= off) ? sh[t - off] : 0;
    __syncthreads();
    sh[t] += x;
    __syncthreads();
  }
  if (t == 255) bsum[blockIdx.x] = sh[255];
  int run = sh[t] - tsum;
#pragma unroll
  for (int i = 0; i < 4; ++i) {
    if (base + i < N_NODES) rp[base + i] = run;
    run += v[i];
  }
}

#define NBLK1 ((N_NODES + 1023) / 1024)  // 98

__global__ __launch_bounds__(128) void scan2(const int* __restrict__ bsum,
                                             int* __restrict__ boff) {
  __shared__ int sh[128];
  int t = threadIdx.x;
  int own = (t < NBLK1) ? bsum[t] : 0;
  sh[t] = own;
  __syncthreads();
  for (int off = 1; off < 128; off <<= 1) {
    int x = (t >= off) ? sh[t - off] : 0;
    __syncthreads();
    sh[t] += x;
    __syncthreads();
  }
  boff[t] = sh[t] - own;
}

__global__ __launch_bounds__(256) void scan3(int* __restrict__ rp,
                                             const int* __restrict__ boff,
                                             int* __restrict__ cursor) {
  int idx = blockIdx.x * 256 + threadIdx.x;
  if (idx < N_NODES) {
    int v = rp[idx] + boff[idx >> 10];
    rp[idx] = v;
    cursor[idx] = v;
  }
  if (idx == 0) rp[N_NODES] = TOT;
}

// scatter + fused edge-weight computation -> one 16B record {src, w01, w23, 0}
__global__ __launch_bounds__(256) void scatter_edges(const int* __restrict__ esrc,
                                                     const int* __restrict__ edst,
                                                     const float* __restrict__ as_buf,
                                                     const float* __restrict__ ad_buf,
                                                     int* __restrict__ cursor,
                                                     uint4* __restrict__ erec) {
  int e = blockIdx.x * 256 + threadIdx.x;
  if (e >= TOT) return;
  int s, d;
  if (e < N_EDGES) { s = esrc[e]; d = edst[e]; }
  else { s = e - N_EDGES; d = s; }
  int p = atomicAdd(&cursor[d], 1);
  float4 a1 = *reinterpret_cast<const float4*>(as_buf + (size_t)s * NHEAD);
  float4 a2 = *reinterpret_cast<const float4*>(ad_buf + (size_t)d * NHEAD);
  float e0 = a1.x + a2.x; e0 = e0 > 0.f ? e0 : NEG_SLOPE * e0;
  float e1 = a1.y + a2.y; e1 = e1 > 0.f ? e1 : NEG_SLOPE * e1;
  float e2 = a1.z + a2.z; e2 = e2 > 0.f ? e2 : NEG_SLOPE * e2;
  float e3 = a1.w + a2.w; e3 = e3 > 0.f ? e3 : NEG_SLOPE * e3;
  // exp(e-4): shift cancels in softmax ratio, keeps fp16 in safe range
  float w0 = __expf(e0 - 4.f), w1 = __expf(e1 - 4.f);
  float w2 = __expf(e2 - 4.f), w3 = __expf(e3 - 4.f);
  uint_t pk01 = __builtin_bit_cast(uint_t, __builtin_amdgcn_cvt_pkrtz(w0, w1));
  uint_t pk23 = __builtin_bit_cast(uint_t, __builtin_amdgcn_cvt_pkrtz(w2, w3));
  erec[p] = make_uint4((uint_t)s, pk01, pk23, 0u);
}

// ---------------- fused softmax + aggregation ----------------
// One wave per node; 4 edges per iteration (2 half-wave records in flight).
__global__ __launch_bounds__(256) void aggregate(const int* __restrict__ rp,
                                                 const uint4* __restrict__ erec,
                                                 const uint2* __restrict__ Hp,
                                                 const float* __restrict__ bias,
                                                 float* __restrict__ out) {
  int n = blockIdx.x * 4 + (threadIdx.x >> 6);
  int lane = threadIdx.x & 63;
  if (n >= N_NODES) return;
  const int half = lane >> 5;
  const uint_t off_lane = (uint_t)(lane & 31) << 4;
  const char* __restrict__ Hb = (const char*)Hp;

  int beg = rp[n], end = rp[n + 1];
  const int last = end - 1;

  float acc[8] = {};
  float den[4] = {};

  int ia = beg + half;     if (ia > last) ia = last;
  int ib = beg + 2 + half; if (ib > last) ib = last;
  uint4 rec_a = erec[ia];
  uint4 rec_b = erec[ib];

  for (int j = beg; j < end; j += 4) {
    uint4 cur_a = rec_a;
    uint4 cur_b = rec_b;
    ia = j + 4 + half; if (ia > last) ia = last;
    ib = j + 6 + half; if (ib > last) ib = last;
    rec_a = erec[ia];
    rec_b = erec[ib];

    uint_t hoff_a = (cur_a.x << 9) | off_lane;
    uint_t hoff_b = (cur_b.x << 9) | off_lane;
    uint4 hva = *reinterpret_cast<const uint4*>(Hb + hoff_a);
    uint4 hvb = *reinterpret_cast<const uint4*>(Hb + hoff_b);

    bool act_a = (j + half) < end;
    bool act_b = (j + 2 + half) < end;
    uint_t wa01u = act_a ? cur_a.y : 0u;
    uint_t wa23u = act_a ? cur_a.z : 0u;
    uint_t wb01u = act_b ? cur_b.y : 0u;
    uint_t wb23u = act_b ? cur_b.z : 0u;

    h2v wa01 = __builtin_bit_cast(h2v, wa01u);
    h2v wa23 = __builtin_bit_cast(h2v, wa23u);
    h2v wb01 = __builtin_bit_cast(h2v, wb01u);
    h2v wb23 = __builtin_bit_cast(h2v, wb23u);

    h2v haa = __builtin_bit_cast(h2v, hva.x);
    h2v hab = __builtin_bit_cast(h2v, hva.y);
    h2v hac = __builtin_bit_cast(h2v, hva.z);
    h2v had = __builtin_bit_cast(h2v, hva.w);

    acc[0] += (float)wa01.x * (float)haa.x;
    acc[1] += (float)wa01.y * (float)haa.y;
    acc[2] += (float)wa23.x * (float)hab.x;
    acc[3] += (float)wa23.y * (float)hab.y;
    acc[4] += (float)wa01.x * (float)hac.x;
    acc[5] += (float)wa01.y * (float)hac.y;
    acc[6] += (float)wa23.x * (float)had.x;
    acc[7] += (float)wa23.y * (float)had.y;
    den[0] += (float)wa01.x;
    den[1] += (float)wa01.y;
    den[2] += (float)wa23.x;
    den[3] += (float)wa23.y;

    h2v hba = __builtin_bit_cast(h2v, hvb.x);
    h2v hbb = __builtin_bit_cast(h2v, hvb.y);
    h2v hbc = __builtin_bit_cast(h2v, hvb.z);
    h2v hbd = __builtin_bit_cast(h2v, hvb.w);

    acc[0] += (float)wb01.x * (float)hba.x;
    acc[1] += (float)wb01.y * (float)hba.y;
    acc[2] += (float)wb23.x * (float)hbb.x;
    acc[3] += (float)wb23.y * (float)hbb.y;
    acc[4] += (float)wb01.x * (float)hbc.x;
    acc[5] += (float)wb01.y * (float)hbc.y;
    acc[6] += (float)wb23.x * (float)hbd.x;
    acc[7] += (float)wb23.y * (float)hbd.y;
    den[0] += (float)wb01.x;
    den[1] += (float)wb01.y;
    den[2] += (float)wb23.x;
    den[3] += (float)wb23.y;
  }

#pragma unroll
  for (int k = 0; k < 8; ++k) acc[k] += __shfl_xor(acc[k], 32, 64);
#pragma unroll
  for (int k = 0; k < 4; ++k) den[k] += __shfl_xor(den[k], 32, 64);

  if (lane < 32) {
    float i0 = 1.f / (den[0] + 1e-30f);
    float i1 = 1.f / (den[1] + 1e-30f);
    float i2 = 1.f / (den[2] + 1e-30f);
    float i3 = 1.f / (den[3] + 1e-30f);
    float2 b2 = *reinterpret_cast<const float2*>(bias + 2 * lane);
    float rA = 0.25f * (acc[0] * i0 + acc[1] * i1 + acc[2] * i2 + acc[3] * i3) + b2.x;
    float rB = 0.25f * (acc[4] * i0 + acc[5] * i1 + acc[6] * i2 + acc[7] * i3) + b2.y;
    *reinterpret_cast<float2*>(out + (size_t)n * CH + 2 * lane) = make_float2(rA, rB);
  }
}

extern "C" void kernel_launch(void* const* d_in, const int* in_sizes, int n_in,
                              void* d_out, int out_size, void* d_ws, size_t ws_size,
                              hipStream_t stream) {
  const float* x       = (const float*)d_in[0];
  const int*   eidx    = (const int*)d_in[1];
  const float* W       = (const float*)d_in[2];
  const float* att_src = (const float*)d_in[3];
  const float* att_dst = (const float*)d_in[4];
  const float* bias    = (const float*)d_in[5];
  float* out = (float*)d_out;

  uint2* Hmp    = (uint2*)d_ws;                               // N*64 uint2 (51.2MB)
  uint4* erec   = (uint4*)(Hmp + (size_t)N_NODES * 64);       // TOT uint4 (27.2MB)
  float* as_buf = (float*)(erec + (size_t)TOT);               // N*4
  float* ad_buf = as_buf + (size_t)N_NODES * NHEAD;           // N*4
  uint4* Wt_arr = (uint4*)(ad_buf + (size_t)N_NODES * NHEAD); // 8192 uint4 (128KB)
  int*   deg    = (int*)(Wt_arr + 8192);                      // N (reused as cursor)
  int*   rp     = deg + N_NODES;                              // N+1
  int*   bsum   = rp + N_NODES + 1;                           // 128
  int*   boff   = bsum + 128;                                 // 128

  const int* esrc = eidx;
  const int* edst = eidx + N_EDGES;

  conv_w<<<32, 256, 0, stream>>>(W, Wt_arr);
  hipMemsetAsync(deg, 0, (size_t)N_NODES * sizeof(int), stream);
  count_deg<<<(N_EDGES / 4 + 255) / 256, 256, 0, stream>>>(edst, deg);

  dim3 ggrid((N_NODES + 63) / 64);
  gemm_mfma<<<ggrid, 256, 0, stream>>>(x, Wt_arr, att_src, att_dst, Hmp, as_buf, ad_buf,
                                       N_NODES);

  scan1<<<NBLK1, 256, 0, stream>>>(deg, rp, bsum);
  scan2<<<1, 128, 0, stream>>>(bsum, boff);
  scan3<<<(N_NODES + 255) / 256, 256, 0, stream>>>(rp, boff, deg /*cursor*/);
  scatter_edges<<<(TOT + 255) / 256, 256, 0, stream>>>(esrc, edst, as_buf, ad_buf,
                                                       deg /*cursor*/, erec);

  aggregate<<<(N_NODES + 3) / 4, 256, 0, stream>>>(rp, erec, Hmp, bias, out);
}

// Round 12
// 332.492 us; speedup vs baseline: 1.0078x; 1.0078x over previous
//
#include <hip/hip_runtime.h>

#define N_NODES 100000
#define N_EDGES 1600000
#define TOT (N_EDGES + N_NODES)
#define IN_CH 256
#define NHEAD 4
#define CH 64
#define HC 256
#define NEG_SLOPE 0.2f

typedef _Float16 half8 __attribute__((ext_vector_type(8)));
typedef _Float16 h2v __attribute__((ext_vector_type(2)));
typedef float f32x4 __attribute__((ext_vector_type(4)));
typedef unsigned short ushort_t;
typedef unsigned int uint_t;

static __device__ __forceinline__ ushort_t f2h(float f) {
  _Float16 h = (_Float16)f;
  return __builtin_bit_cast(ushort_t, h);
}

// async global->LDS, 16B per lane (dest = wave-uniform base + lane*16)
static __device__ __forceinline__ void gload_lds16(const char* g, char* l) {
  __builtin_amdgcn_global_load_lds(
      (const __attribute__((address_space(1))) unsigned int*)g,
      (__attribute__((address_space(3))) unsigned int*)l, 16, 0, 0);
}

// ---------------- W fp32 [K=256][N=256] -> Wt_arr, MFMA-fragment-major ----------------
// uint4 index f = (ks*16 + n)*64 + lane ; halfs j=0..7 :
//   W[ ks*32 + (lane>>4)*8 + j ][ n*16 + (lane&15) ]
__global__ __launch_bounds__(256) void conv_w(const float* __restrict__ W,
                                              uint4* __restrict__ Wt_arr) {
  int id = blockIdx.x * 256 + threadIdx.x;  // 0..8191
  int lane = id & 63;
  int n = (id >> 6) & 15;
  int ks = id >> 10;
  int col = n * 16 + (lane & 15);
  int kbase = ks * 32 + (lane >> 4) * 8;
  ushort_t h[8];
#pragma unroll
  for (int j = 0; j < 8; ++j) h[j] = f2h(W[(size_t)(kbase + j) * HC + col]);
  uint4 u;
  u.x = (uint_t)h[0] | ((uint_t)h[1] << 16);
  u.y = (uint_t)h[2] | ((uint_t)h[3] << 16);
  u.z = (uint_t)h[4] | ((uint_t)h[5] << 16);
  u.w = (uint_t)h[6] | ((uint_t)h[7] << 16);
  Wt_arr[id] = u;
}

// ---------------- MFMA GEMM: 8 waves/128 rows, LDS-B dbuf, reg-A ----------------
// B tile (16KB/k-step) staged once per BLOCK via global_load_lds (CU-shared);
// A loaded straight to regs (per-lane rows), depth-1 prefetch; 1 barrier/k-step.
__global__ __launch_bounds__(512) void gemm_mfma(const float* __restrict__ X,
                                                 const uint4* __restrict__ Wt_arr,
                                                 const float* __restrict__ att_src,
                                                 const float* __restrict__ att_dst,
                                                 uint2* __restrict__ Hmp,
                                                 float* __restrict__ as_out,
                                                 float* __restrict__ ad_out, int M) {
  __shared__ uint4 Bs[2][1024];  // 2 x 16 KB, [n*64 + lane] linear
  const int tid = threadIdx.x;
  const int lane = tid & 63;
  const int wid = tid >> 6;   // 0..7
  const int l16 = lane & 15;
  const int lhi = lane >> 4;
  const int row0 = blockIdx.x * 128;

  int rowA = row0 + wid * 16 + l16;
  if (rowA >= M) rowA = M - 1;  // clamp; stores guarded
  const float* __restrict__ xr = X + (size_t)rowA * IN_CH + lhi * 8;

  const char* __restrict__ wsrc = (const char*)Wt_arr;
  char* bd0 = (char*)&Bs[0][0] + tid * 16;
  char* bd1 = (char*)&Bs[1][0] + tid * 16;

  // prologue: stage B step-0, load A step-0
  gload_lds16(wsrc + tid * 16, bd0);
  gload_lds16(wsrc + 8192 + tid * 16, bd0 + 8192);
  float4 xa = *reinterpret_cast<const float4*>(xr);
  float4 xb = *reinterpret_cast<const float4*>(xr + 4);

  f32x4 acc[16] = {};
  int cur = 0;

#pragma unroll
  for (int ks = 0; ks < 8; ++ks) {
    __syncthreads();  // drains prev stage: B[cur] ready in LDS

    float4 na, nb;
    if (ks < 7) {
      // issue next B stage + next A loads EARLY (fly under the MFMAs below)
      char* bd = (cur == 0) ? bd1 : bd0;
      const char* s = wsrc + (ks + 1) * 16384 + tid * 16;
      gload_lds16(s, bd);
      gload_lds16(s + 8192, bd + 8192);
      na = *reinterpret_cast<const float4*>(xr + (ks + 1) * 32);
      nb = *reinterpret_cast<const float4*>(xr + (ks + 1) * 32 + 4);
    }

    uint4 ua;
    ua.x = __builtin_bit_cast(uint_t, __builtin_amdgcn_cvt_pkrtz(xa.x, xa.y));
    ua.y = __builtin_bit_cast(uint_t, __builtin_amdgcn_cvt_pkrtz(xa.z, xa.w));
    ua.z = __builtin_bit_cast(uint_t, __builtin_amdgcn_cvt_pkrtz(xb.x, xb.y));
    ua.w = __builtin_bit_cast(uint_t, __builtin_amdgcn_cvt_pkrtz(xb.z, xb.w));
    half8 a = __builtin_bit_cast(half8, ua);

    const char* bbase = (const char*)&Bs[cur][0];
#pragma unroll
    for (int n = 0; n < 16; ++n) {
      half8 b = *reinterpret_cast<const half8*>(bbase + n * 1024 + lane * 16);
      acc[n] = __builtin_amdgcn_mfma_f32_16x16x32_f16(a, b, acc[n], 0, 0, 0);
    }
    xa = na; xb = nb;
    cur ^= 1;
  }

  // epilogue: pack Hmp + fused attention dots
  float attS[16], attD[16];
#pragma unroll
  for (int n = 0; n < 16; ++n) {
    attS[n] = att_src[n * 16 + l16];
    attD[n] = att_dst[n * 16 + l16];
  }

#pragma unroll
  for (int r = 0; r < 4; ++r) {
    int grow = row0 + wid * 16 + lhi * 4 + r;
    if (grow < M) {
#pragma unroll
      for (int n2 = 0; n2 < 4; ++n2) {
        uint_t pk01 = __builtin_bit_cast(uint_t,
            __builtin_amdgcn_cvt_pkrtz(acc[n2][r], acc[n2 + 4][r]));
        uint_t pk23 = __builtin_bit_cast(uint_t,
            __builtin_amdgcn_cvt_pkrtz(acc[n2 + 8][r], acc[n2 + 12][r]));
        Hmp[(size_t)grow * 64 + n2 * 16 + l16] = make_uint2(pk01, pk23);
      }
      float sv[4] = {0.f, 0.f, 0.f, 0.f}, dv[4] = {0.f, 0.f, 0.f, 0.f};
#pragma unroll
      for (int h = 0; h < 4; ++h)
#pragma unroll
        for (int j = 0; j < 4; ++j) {
          sv[h] += acc[h * 4 + j][r] * attS[h * 4 + j];
          dv[h] += acc[h * 4 + j][r] * attD[h * 4 + j];
        }
#pragma unroll
      for (int off = 1; off < 16; off <<= 1)
#pragma unroll
        for (int h = 0; h < 4; ++h) {
          sv[h] += __shfl_xor(sv[h], off, 16);
          dv[h] += __shfl_xor(dv[h], off, 16);
        }
      if (l16 == 0) {
#pragma unroll
        for (int h = 0; h < 4; ++h) {
          as_out[(size_t)grow * 4 + h] = sv[h];
          ad_out[(size_t)grow * 4 + h] = dv[h];
        }
      }
    }
  }
}

// ---------------- CSR build ----------------
__global__ __launch_bounds__(256) void count_deg(const int* __restrict__ edst,
                                                 int* __restrict__ deg) {
  int t = blockIdx.x * 256 + threadIdx.x;
  if (t >= N_EDGES / 4) return;
  int4 d4 = reinterpret_cast<const int4*>(edst)[t];
  atomicAdd(&deg[d4.x], 1);
  atomicAdd(&deg[d4.y], 1);
  atomicAdd(&deg[d4.z], 1);
  atomicAdd(&deg[d4.w], 1);
}

// scan1 adds the +1 self-loop per node inline.
__global__ __launch_bounds__(256) void scan1(const int* __restrict__ deg,
                                             int* __restrict__ rp,
                                             int* __restrict__ bsum) {
  __shared__ int sh[256];
  int t = threadIdx.x;
  int base = blockIdx.x * 1024 + t * 4;
  int v[4];
#pragma unroll
  for (int i = 0; i < 4; ++i) v[i] = (base + i < N_NODES) ? (deg[base + i] + 1) : 0;
  int tsum = v[0] + v[1] + v[2] + v[3];
  sh[t] = tsum;
  __syncthreads();
  for (int off = 1; off < 256; off <<= 1) {
    int x = (t >= off) ? sh[t - off] : 0;
    __syncthreads();
    sh[t] += x;
    __syncthreads();
  }
  if (t == 255) bsum[blockIdx.x] = sh[255];
  int run = sh[t] - tsum;
#pragma unroll
  for (int i = 0; i < 4; ++i) {
    if (base + i < N_NODES) rp[base + i] = run;
    run += v[i];
  }
}

#define NBLK1 ((N_NODES + 1023) / 1024)  // 98

__global__ __launch_bounds__(128) void scan2(const int* __restrict__ bsum,
                                             int* __restrict__ boff) {
  __shared__ int sh[128];
  int t = threadIdx.x;
  int own = (t < NBLK1) ? bsum[t] : 0;
  sh[t] = own;
  __syncthreads();
  for (int off = 1; off < 128; off <<= 1) {
    int x = (t >= off) ? sh[t - off] : 0;
    __syncthreads();
    sh[t] += x;
    __syncthreads();
  }
  boff[t] = sh[t] - own;
}

__global__ __launch_bounds__(256) void scan3(int* __restrict__ rp,
                                             const int* __restrict__ boff,
                                             int* __restrict__ cursor) {
  int idx = blockIdx.x * 256 + threadIdx.x;
  if (idx < N_NODES) {
    int v = rp[idx] + boff[idx >> 10];
    rp[idx] = v;
    cursor[idx] = v;
  }
  if (idx == 0) rp[N_NODES] = TOT;
}

// scatter + fused edge-weight computation -> one 16B record {src, w01, w23, 0}
// also zero-fills the 8 pad records past TOT (enables clamp-free prefetch).
__global__ __launch_bounds__(256) void scatter_edges(const int* __restrict__ esrc,
                                                     const int* __restrict__ edst,
                                                     const float* __restrict__ as_buf,
                                                     const float* __restrict__ ad_buf,
                                                     int* __restrict__ cursor,
                                                     uint4* __restrict__ erec) {
  int e = blockIdx.x * 256 + threadIdx.x;
  if (e >= TOT) return;
  if (e < 8) erec[TOT + e] = make_uint4(0u, 0u, 0u, 0u);
  int s, d;
  if (e < N_EDGES) { s = esrc[e]; d = edst[e]; }
  else { s = e - N_EDGES; d = s; }
  int p = atomicAdd(&cursor[d], 1);
  float4 a1 = *reinterpret_cast<const float4*>(as_buf + (size_t)s * NHEAD);
  float4 a2 = *reinterpret_cast<const float4*>(ad_buf + (size_t)d * NHEAD);
  float e0 = a1.x + a2.x; e0 = e0 > 0.f ? e0 : NEG_SLOPE * e0;
  float e1 = a1.y + a2.y; e1 = e1 > 0.f ? e1 : NEG_SLOPE * e1;
  float e2 = a1.z + a2.z; e2 = e2 > 0.f ? e2 : NEG_SLOPE * e2;
  float e3 = a1.w + a2.w; e3 = e3 > 0.f ? e3 : NEG_SLOPE * e3;
  // exp(e-4): shift cancels in softmax ratio, keeps fp16 in safe range
  float w0 = __expf(e0 - 4.f), w1 = __expf(e1 - 4.f);
  float w2 = __expf(e2 - 4.f), w3 = __expf(e3 - 4.f);
  uint_t pk01 = __builtin_bit_cast(uint_t, __builtin_amdgcn_cvt_pkrtz(w0, w1));
  uint_t pk23 = __builtin_bit_cast(uint_t, __builtin_amdgcn_cvt_pkrtz(w2, w3));
  erec[p] = make_uint4((uint_t)s, pk01, pk23, 0u);
}

// ---------------- fused softmax + aggregation ----------------
// One wave per node; 4 edges/iter (2 half-wave records in flight);
// clamp-free prefetch via zero-padded erec (+8 records).
__global__ __launch_bounds__(256) void aggregate(const int* __restrict__ rp,
                                                 const uint4* __restrict__ erec,
                                                 const uint2* __restrict__ Hp,
                                                 const float* __restrict__ bias,
                                                 float* __restrict__ out) {
  int n = blockIdx.x * 4 + (threadIdx.x >> 6);
  int lane = threadIdx.x & 63;
  if (n >= N_NODES) return;
  const int half = lane >> 5;
  const uint_t off_lane = (uint_t)(lane & 31) << 4;
  const char* __restrict__ Hb = (const char*)Hp;

  int beg = rp[n], end = rp[n + 1];

  float acc[8] = {};
  float den[4] = {};

  const uint4* __restrict__ ep = erec + beg + half;
  uint4 rec_a = ep[0];
  uint4 rec_b = ep[2];

  for (int j = beg; j < end; j += 4, ep += 4) {
    uint4 cur_a = rec_a;
    uint4 cur_b = rec_b;
    rec_a = ep[4];  // pad-safe: max index < TOT+8
    rec_b = ep[6];

    uint_t hoff_a = (cur_a.x << 9) | off_lane;
    uint_t hoff_b = (cur_b.x << 9) | off_lane;
    uint4 hva = *reinterpret_cast<const uint4*>(Hb + hoff_a);
    uint4 hvb = *reinterpret_cast<const uint4*>(Hb + hoff_b);

    bool act_a = (j + half) < end;
    bool act_b = (j + 2 + half) < end;
    uint_t wa01u = act_a ? cur_a.y : 0u;
    uint_t wa23u = act_a ? cur_a.z : 0u;
    uint_t wb01u = act_b ? cur_b.y : 0u;
    uint_t wb23u = act_b ? cur_b.z : 0u;

    h2v wa01 = __builtin_bit_cast(h2v, wa01u);
    h2v wa23 = __builtin_bit_cast(h2v, wa23u);
    h2v wb01 = __builtin_bit_cast(h2v, wb01u);
    h2v wb23 = __builtin_bit_cast(h2v, wb23u);

    h2v haa = __builtin_bit_cast(h2v, hva.x);
    h2v hab = __builtin_bit_cast(h2v, hva.y);
    h2v hac = __builtin_bit_cast(h2v, hva.z);
    h2v had = __builtin_bit_cast(h2v, hva.w);

    acc[0] += (float)wa01.x * (float)haa.x;
    acc[1] += (float)wa01.y * (float)haa.y;
    acc[2] += (float)wa23.x * (float)hab.x;
    acc[3] += (float)wa23.y * (float)hab.y;
    acc[4] += (float)wa01.x * (float)hac.x;
    acc[5] += (float)wa01.y * (float)hac.y;
    acc[6] += (float)wa23.x * (float)had.x;
    acc[7] += (float)wa23.y * (float)had.y;
    den[0] += (float)wa01.x;
    den[1] += (float)wa01.y;
    den[2] += (float)wa23.x;
    den[3] += (float)wa23.y;

    h2v hba = __builtin_bit_cast(h2v, hvb.x);
    h2v hbb = __builtin_bit_cast(h2v, hvb.y);
    h2v hbc = __builtin_bit_cast(h2v, hvb.z);
    h2v hbd = __builtin_bit_cast(h2v, hvb.w);

    acc[0] += (float)wb01.x * (float)hba.x;
    acc[1] += (float)wb01.y * (float)hba.y;
    acc[2] += (float)wb23.x * (float)hbb.x;
    acc[3] += (float)wb23.y * (float)hbb.y;
    acc[4] += (float)wb01.x * (float)hbc.x;
    acc[5] += (float)wb01.y * (float)hbc.y;
    acc[6] += (float)wb23.x * (float)hbd.x;
    acc[7] += (float)wb23.y * (float)hbd.y;
    den[0] += (float)wb01.x;
    den[1] += (float)wb01.y;
    den[2] += (float)wb23.x;
    den[3] += (float)wb23.y;
  }

#pragma unroll
  for (int k = 0; k < 8; ++k) acc[k] += __shfl_xor(acc[k], 32, 64);
#pragma unroll
  for (int k = 0; k < 4; ++k) den[k] += __shfl_xor(den[k], 32, 64);

  if (lane < 32) {
    float i0 = 1.f / (den[0] + 1e-30f);
    float i1 = 1.f / (den[1] + 1e-30f);
    float i2 = 1.f / (den[2] + 1e-30f);
    float i3 = 1.f / (den[3] + 1e-30f);
    float2 b2 = *reinterpret_cast<const float2*>(bias + 2 * lane);
    float rA = 0.25f * (acc[0] * i0 + acc[1] * i1 + acc[2] * i2 + acc[3] * i3) + b2.x;
    float rB = 0.25f * (acc[4] * i0 + acc[5] * i1 + acc[6] * i2 + acc[7] * i3) + b2.y;
    *reinterpret_cast<float2*>(out + (size_t)n * CH + 2 * lane) = make_float2(rA, rB);
  }
}

extern "C" void kernel_launch(void* const* d_in, const int* in_sizes, int n_in,
                              void* d_out, int out_size, void* d_ws, size_t ws_size,
                              hipStream_t stream) {
  const float* x       = (const float*)d_in[0];
  const int*   eidx    = (const int*)d_in[1];
  const float* W       = (const float*)d_in[2];
  const float* att_src = (const float*)d_in[3];
  const float* att_dst = (const float*)d_in[4];
  const float* bias    = (const float*)d_in[5];
  float* out = (float*)d_out;

  uint2* Hmp    = (uint2*)d_ws;                               // N*64 uint2 (51.2MB)
  uint4* erec   = (uint4*)(Hmp + (size_t)N_NODES * 64);       // TOT+8 uint4 (27.2MB)
  float* as_buf = (float*)(erec + (size_t)TOT + 8);           // N*4
  float* ad_buf = as_buf + (size_t)N_NODES * NHEAD;           // N*4
  uint4* Wt_arr = (uint4*)(ad_buf + (size_t)N_NODES * NHEAD); // 8192 uint4 (128KB)
  int*   deg    = (int*)(Wt_arr + 8192);                      // N (reused as cursor)
  int*   rp     = deg + N_NODES;                              // N+1
  int*   bsum   = rp + N_NODES + 1;                           // 128
  int*   boff   = bsum + 128;                                 // 128

  const int* esrc = eidx;
  const int* edst = eidx + N_EDGES;

  conv_w<<<32, 256, 0, stream>>>(W, Wt_arr);
  hipMemsetAsync(deg, 0, (size_t)N_NODES * sizeof(int), stream);
  count_deg<<<(N_EDGES / 4 + 255) / 256, 256, 0, stream>>>(edst, deg);

  dim3 ggrid((N_NODES + 127) / 128);  // 782 blocks x 512 threads
  gemm_mfma<<<ggrid, 512, 0, stream>>>(x, Wt_arr, att_src, att_dst, Hmp, as_buf, ad_buf,
                                       N_NODES);

  scan1<<<NBLK1, 256, 0, stream>>>(deg, rp, bsum);
  scan2<<<1, 128, 0, stream>>>(bsum, boff);
  scan3<<<(N_NODES + 255) / 256, 256, 0, stream>>>(rp, boff, deg /*cursor*/);
  scatter_edges<<<(TOT + 255) / 256, 256, 0, stream>>>(esrc, edst, as_buf, ad_buf,
                                                       deg /*cursor*/, erec);

  aggregate<<<(N_NODES + 3) / 4, 256, 0, stream>>>(rp, erec, Hmp, bias, out);
}

// Round 13
// 328.684 us; speedup vs baseline: 1.0194x; 1.0116x over previous
//
#include <hip/hip_runtime.h>

#define N_NODES 100000
#define N_EDGES 1600000
#define TOT (N_EDGES + N_NODES)
#define IN_CH 256
#define NHEAD 4
#define CH 64
#define HC 256
#define NEG_SLOPE 0.2f

typedef _Float16 half8 __attribute__((ext_vector_type(8)));
typedef _Float16 h2v __attribute__((ext_vector_type(2)));
typedef float f32x4 __attribute__((ext_vector_type(4)));
typedef unsigned short ushort_t;
typedef unsigned int uint_t;

static __device__ __forceinline__ ushort_t f2h(float f) {
  _Float16 h = (_Float16)f;
  return __builtin_bit_cast(ushort_t, h);
}

// async global->LDS, 16B per lane (dest = wave-uniform base + lane*16)
static __device__ __forceinline__ void gload_lds16(const char* g, char* l) {
  __builtin_amdgcn_global_load_lds(
      (const __attribute__((address_space(1))) unsigned int*)g,
      (__attribute__((address_space(3))) unsigned int*)l, 16, 0, 0);
}

// ---------------- W fp32 [K=256][N=256] -> Wt_arr, MFMA-fragment-major ----------------
// uint4 index f = (ks*16 + n)*64 + lane ; halfs j=0..7 :
//   W[ ks*32 + (lane>>4)*8 + j ][ n*16 + (lane&15) ]
__global__ __launch_bounds__(256) void conv_w(const float* __restrict__ W,
                                              uint4* __restrict__ Wt_arr) {
  int id = blockIdx.x * 256 + threadIdx.x;  // 0..8191
  int lane = id & 63;
  int n = (id >> 6) & 15;
  int ks = id >> 10;
  int col = n * 16 + (lane & 15);
  int kbase = ks * 32 + (lane >> 4) * 8;
  ushort_t h[8];
#pragma unroll
  for (int j = 0; j < 8; ++j) h[j] = f2h(W[(size_t)(kbase + j) * HC + col]);
  uint4 u;
  u.x = (uint_t)h[0] | ((uint_t)h[1] << 16);
  u.y = (uint_t)h[2] | ((uint_t)h[3] << 16);
  u.z = (uint_t)h[4] | ((uint_t)h[5] << 16);
  u.w = (uint_t)h[6] | ((uint_t)h[7] << 16);
  Wt_arr[id] = u;
}

// ---------------- MFMA GEMM: coalesced DMA staging for A AND B ----------------
// 256 threads = 4 waves; block = 64 rows; wave = 16 rows x 256 cols.
// A fp32 tile (8KB/k-step) staged via LINEAR global_load_lds (16 lines/instr,
// coalescing optimum) with XOR-swizzled SOURCE (slot ^= row&7) so the
// stride-128B fragment ds_read is a free 2-way bank conflict (T2, rule #21).
// B fragment-major tile (16KB/k-step) staged linearly as before. Double-buffered,
// one barrier per k-step.
__global__ __launch_bounds__(256) void gemm_mfma(const float* __restrict__ X,
                                                 const uint4* __restrict__ Wt_arr,
                                                 const float* __restrict__ att_src,
                                                 const float* __restrict__ att_dst,
                                                 uint2* __restrict__ Hmp,
                                                 float* __restrict__ as_out,
                                                 float* __restrict__ ad_out, int M) {
  __shared__ uint4 Bs[2][1024];                    // 2 x 16 KB
  __shared__ __align__(16) float As[2][2048];      // 2 x 8 KB (64 rows x 32 f32)
  const int tid = threadIdx.x;
  const int lane = tid & 63;
  const int wid = tid >> 6;
  const int l16 = lane & 15;
  const int lhi = lane >> 4;
  const int row0 = blockIdx.x * 64;

  // A-DMA: linear dest chunk idx = tid (+256 for call 1); row=idx>>3, slot=idx&7.
  // source slot is XOR-swizzled: X[row][ks*32 + ((slot^(row&7))*4) ..]
  const int arow = tid >> 3;
  const int aslot = tid & 7;
  int ga0 = row0 + arow;       if (ga0 >= M) ga0 = M - 1;
  int ga1 = row0 + arow + 32;  if (ga1 >= M) ga1 = M - 1;
  const int sslot = aslot ^ (arow & 7);  // (arow+32)&7 == arow&7
  const char* asrc0 = (const char*)X + (size_t)ga0 * 1024 + (sslot << 4);
  const char* asrc1 = (const char*)X + (size_t)ga1 * 1024 + (sslot << 4);
  char* adst0 = (char*)&As[0][0] + tid * 16;
  char* adst1 = (char*)&As[1][0] + tid * 16;

  const char* __restrict__ wsrc = (const char*)Wt_arr;
  char* bd0 = (char*)&Bs[0][0] + tid * 16;
  char* bd1 = (char*)&Bs[1][0] + tid * 16;

  // fragment read geometry (XOR-swizzled)
  const int frow = wid * 16 + l16;
  const int sw = frow & 7;
  const int fo0 = frow * 32 + (((2 * lhi + 0) ^ sw) << 2);
  const int fo1 = frow * 32 + (((2 * lhi + 1) ^ sw) << 2);

  // prologue: stage k-step 0 into buffer 0
  gload_lds16(asrc0, adst0);
  gload_lds16(asrc1, adst0 + 4096);
  gload_lds16(wsrc + tid * 16,         bd0);
  gload_lds16(wsrc + 4096 + tid * 16,  bd0 + 4096);
  gload_lds16(wsrc + 8192 + tid * 16,  bd0 + 8192);
  gload_lds16(wsrc + 12288 + tid * 16, bd0 + 12288);

  f32x4 acc[16] = {};
  int cur = 0;

#pragma unroll
  for (int ks = 0; ks < 8; ++ks) {
    __syncthreads();  // drains prev-stage DMA: A[cur], B[cur] ready

    if (ks < 7) {
      // issue next-stage DMA EARLY (flies under this step's MFMAs)
      char* ad = (cur == 0) ? adst1 : adst0;
      gload_lds16(asrc0 + (ks + 1) * 128, ad);
      gload_lds16(asrc1 + (ks + 1) * 128, ad + 4096);
      char* bd = (cur == 0) ? bd1 : bd0;
      const char* s = wsrc + (ks + 1) * 16384 + tid * 16;
      gload_lds16(s,         bd);
      gload_lds16(s + 4096,  bd + 4096);
      gload_lds16(s + 8192,  bd + 8192);
      gload_lds16(s + 12288, bd + 12288);
    }

    // A fragment: two swizzled 16B LDS reads + pkrtz -> half8
    const float* Ab = &As[cur][0];
    float4 f0 = *reinterpret_cast<const float4*>(Ab + fo0);
    float4 f1 = *reinterpret_cast<const float4*>(Ab + fo1);
    uint4 ua;
    ua.x = __builtin_bit_cast(uint_t, __builtin_amdgcn_cvt_pkrtz(f0.x, f0.y));
    ua.y = __builtin_bit_cast(uint_t, __builtin_amdgcn_cvt_pkrtz(f0.z, f0.w));
    ua.z = __builtin_bit_cast(uint_t, __builtin_amdgcn_cvt_pkrtz(f1.x, f1.y));
    ua.w = __builtin_bit_cast(uint_t, __builtin_amdgcn_cvt_pkrtz(f1.z, f1.w));
    half8 a = __builtin_bit_cast(half8, ua);

    const char* bbase = (const char*)&Bs[cur][0];
#pragma unroll
    for (int n = 0; n < 16; ++n) {
      half8 b = *reinterpret_cast<const half8*>(bbase + n * 1024 + lane * 16);
      acc[n] = __builtin_amdgcn_mfma_f32_16x16x32_f16(a, b, acc[n], 0, 0, 0);
    }
    cur ^= 1;
  }

  // epilogue: pack Hmp + fused attention dots
  float attS[16], attD[16];
#pragma unroll
  for (int n = 0; n < 16; ++n) {
    attS[n] = att_src[n * 16 + l16];
    attD[n] = att_dst[n * 16 + l16];
  }

#pragma unroll
  for (int r = 0; r < 4; ++r) {
    int grow = row0 + wid * 16 + lhi * 4 + r;
    if (grow < M) {
#pragma unroll
      for (int n2 = 0; n2 < 4; ++n2) {
        uint_t pk01 = __builtin_bit_cast(uint_t,
            __builtin_amdgcn_cvt_pkrtz(acc[n2][r], acc[n2 + 4][r]));
        uint_t pk23 = __builtin_bit_cast(uint_t,
            __builtin_amdgcn_cvt_pkrtz(acc[n2 + 8][r], acc[n2 + 12][r]));
        Hmp[(size_t)grow * 64 + n2 * 16 + l16] = make_uint2(pk01, pk23);
      }
      float sv[4] = {0.f, 0.f, 0.f, 0.f}, dv[4] = {0.f, 0.f, 0.f, 0.f};
#pragma unroll
      for (int h = 0; h < 4; ++h)
#pragma unroll
        for (int j = 0; j < 4; ++j) {
          sv[h] += acc[h * 4 + j][r] * attS[h * 4 + j];
          dv[h] += acc[h * 4 + j][r] * attD[h * 4 + j];
        }
#pragma unroll
      for (int off = 1; off < 16; off <<= 1)
#pragma unroll
        for (int h = 0; h < 4; ++h) {
          sv[h] += __shfl_xor(sv[h], off, 16);
          dv[h] += __shfl_xor(dv[h], off, 16);
        }
      if (l16 == 0) {
#pragma unroll
        for (int h = 0; h < 4; ++h) {
          as_out[(size_t)grow * 4 + h] = sv[h];
          ad_out[(size_t)grow * 4 + h] = dv[h];
        }
      }
    }
  }
}

// ---------------- CSR build ----------------
__global__ __launch_bounds__(256) void count_deg(const int* __restrict__ edst,
                                                 int* __restrict__ deg) {
  int t = blockIdx.x * 256 + threadIdx.x;
  if (t >= N_EDGES / 4) return;
  int4 d4 = reinterpret_cast<const int4*>(edst)[t];
  atomicAdd(&deg[d4.x], 1);
  atomicAdd(&deg[d4.y], 1);
  atomicAdd(&deg[d4.z], 1);
  atomicAdd(&deg[d4.w], 1);
}

// scan1 adds the +1 self-loop per node inline.
__global__ __launch_bounds__(256) void scan1(const int* __restrict__ deg,
                                             int* __restrict__ rp,
                                             int* __restrict__ bsum) {
  __shared__ int sh[256];
  int t = threadIdx.x;
  int base = blockIdx.x * 1024 + t * 4;
  int v[4];
#pragma unroll
  for (int i = 0; i < 4; ++i) v[i] = (base + i < N_NODES) ? (deg[base + i] + 1) : 0;
  int tsum = v[0] + v[1] + v[2] + v[3];
  sh[t] = tsum;
  __syncthreads();
  for (int off = 1; off < 256; off <<= 1) {
    int x = (t >= off) ? sh[t - off] : 0;
    __syncthreads();
    sh[t] += x;
    __syncthreads();
  }
  if (t == 255) bsum[blockIdx.x] = sh[255];
  int run = sh[t] - tsum;
#pragma unroll
  for (int i = 0; i < 4; ++i) {
    if (base + i < N_NODES) rp[base + i] = run;
    run += v[i];
  }
}

#define NBLK1 ((N_NODES + 1023) / 1024)  // 98

__global__ __launch_bounds__(128) void scan2(const int* __restrict__ bsum,
                                             int* __restrict__ boff) {
  __shared__ int sh[128];
  int t = threadIdx.x;
  int own = (t < NBLK1) ? bsum[t] : 0;
  sh[t] = own;
  __syncthreads();
  for (int off = 1; off < 128; off <<= 1) {
    int x = (t >= off) ? sh[t - off] : 0;
    __syncthreads();
    sh[t] += x;
    __syncthreads();
  }
  boff[t] = sh[t] - own;
}

__global__ __launch_bounds__(256) void scan3(int* __restrict__ rp,
                                             const int* __restrict__ boff,
                                             int* __restrict__ cursor) {
  int idx = blockIdx.x * 256 + threadIdx.x;
  if (idx < N_NODES) {
    int v = rp[idx] + boff[idx >> 10];
    rp[idx] = v;
    cursor[idx] = v;
  }
  if (idx == 0) rp[N_NODES] = TOT;
}

// scatter + fused edge-weight computation -> one 16B record {src, w01, w23, 0}
__global__ __launch_bounds__(256) void scatter_edges(const int* __restrict__ esrc,
                                                     const int* __restrict__ edst,
                                                     const float* __restrict__ as_buf,
                                                     const float* __restrict__ ad_buf,
                                                     int* __restrict__ cursor,
                                                     uint4* __restrict__ erec) {
  int e = blockIdx.x * 256 + threadIdx.x;
  if (e >= TOT) return;
  int s, d;
  if (e < N_EDGES) { s = esrc[e]; d = edst[e]; }
  else { s = e - N_EDGES; d = s; }
  int p = atomicAdd(&cursor[d], 1);
  float4 a1 = *reinterpret_cast<const float4*>(as_buf + (size_t)s * NHEAD);
  float4 a2 = *reinterpret_cast<const float4*>(ad_buf + (size_t)d * NHEAD);
  float e0 = a1.x + a2.x; e0 = e0 > 0.f ? e0 : NEG_SLOPE * e0;
  float e1 = a1.y + a2.y; e1 = e1 > 0.f ? e1 : NEG_SLOPE * e1;
  float e2 = a1.z + a2.z; e2 = e2 > 0.f ? e2 : NEG_SLOPE * e2;
  float e3 = a1.w + a2.w; e3 = e3 > 0.f ? e3 : NEG_SLOPE * e3;
  // exp(e-4): shift cancels in softmax ratio, keeps fp16 in safe range
  float w0 = __expf(e0 - 4.f), w1 = __expf(e1 - 4.f);
  float w2 = __expf(e2 - 4.f), w3 = __expf(e3 - 4.f);
  uint_t pk01 = __builtin_bit_cast(uint_t, __builtin_amdgcn_cvt_pkrtz(w0, w1));
  uint_t pk23 = __builtin_bit_cast(uint_t, __builtin_amdgcn_cvt_pkrtz(w2, w3));
  erec[p] = make_uint4((uint_t)s, pk01, pk23, 0u);
}

// ---------------- fused softmax + aggregation (R11 clamped-prefetch form) ----------
__global__ __launch_bounds__(256) void aggregate(const int* __restrict__ rp,
                                                 const uint4* __restrict__ erec,
                                                 const uint2* __restrict__ Hp,
                                                 const float* __restrict__ bias,
                                                 float* __restrict__ out) {
  int n = blockIdx.x * 4 + (threadIdx.x >> 6);
  int lane = threadIdx.x & 63;
  if (n >= N_NODES) return;
  const int half = lane >> 5;
  const uint_t off_lane = (uint_t)(lane & 31) << 4;
  const char* __restrict__ Hb = (const char*)Hp;

  int beg = rp[n], end = rp[n + 1];
  const int last = end - 1;

  float acc[8] = {};
  float den[4] = {};

  int ia = beg + half;     if (ia > last) ia = last;
  int ib = beg + 2 + half; if (ib > last) ib = last;
  uint4 rec_a = erec[ia];
  uint4 rec_b = erec[ib];

  for (int j = beg; j < end; j += 4) {
    uint4 cur_a = rec_a;
    uint4 cur_b = rec_b;
    ia = j + 4 + half; if (ia > last) ia = last;
    ib = j + 6 + half; if (ib > last) ib = last;
    rec_a = erec[ia];
    rec_b = erec[ib];

    uint_t hoff_a = (cur_a.x << 9) | off_lane;
    uint_t hoff_b = (cur_b.x << 9) | off_lane;
    uint4 hva = *reinterpret_cast<const uint4*>(Hb + hoff_a);
    uint4 hvb = *reinterpret_cast<const uint4*>(Hb + hoff_b);

    bool act_a = (j + half) < end;
    bool act_b = (j + 2 + half) < end;
    uint_t wa01u = act_a ? cur_a.y : 0u;
    uint_t wa23u = act_a ? cur_a.z : 0u;
    uint_t wb01u = act_b ? cur_b.y : 0u;
    uint_t wb23u = act_b ? cur_b.z : 0u;

    h2v wa01 = __builtin_bit_cast(h2v, wa01u);
    h2v wa23 = __builtin_bit_cast(h2v, wa23u);
    h2v wb01 = __builtin_bit_cast(h2v, wb01u);
    h2v wb23 = __builtin_bit_cast(h2v, wb23u);

    h2v haa = __builtin_bit_cast(h2v, hva.x);
    h2v hab = __builtin_bit_cast(h2v, hva.y);
    h2v hac = __builtin_bit_cast(h2v, hva.z);
    h2v had = __builtin_bit_cast(h2v, hva.w);

    acc[0] += (float)wa01.x * (float)haa.x;
    acc[1] += (float)wa01.y * (float)haa.y;
    acc[2] += (float)wa23.x * (float)hab.x;
    acc[3] += (float)wa23.y * (float)hab.y;
    acc[4] += (float)wa01.x * (float)hac.x;
    acc[5] += (float)wa01.y * (float)hac.y;
    acc[6] += (float)wa23.x * (float)had.x;
    acc[7] += (float)wa23.y * (float)had.y;
    den[0] += (float)wa01.x;
    den[1] += (float)wa01.y;
    den[2] += (float)wa23.x;
    den[3] += (float)wa23.y;

    h2v hba = __builtin_bit_cast(h2v, hvb.x);
    h2v hbb = __builtin_bit_cast(h2v, hvb.y);
    h2v hbc = __builtin_bit_cast(h2v, hvb.z);
    h2v hbd = __builtin_bit_cast(h2v, hvb.w);

    acc[0] += (float)wb01.x * (float)hba.x;
    acc[1] += (float)wb01.y * (float)hba.y;
    acc[2] += (float)wb23.x * (float)hbb.x;
    acc[3] += (float)wb23.y * (float)hbb.y;
    acc[4] += (float)wb01.x * (float)hbc.x;
    acc[5] += (float)wb01.y * (float)hbc.y;
    acc[6] += (float)wb23.x * (float)hbd.x;
    acc[7] += (float)wb23.y * (float)hbd.y;
    den[0] += (float)wb01.x;
    den[1] += (float)wb01.y;
    den[2] += (float)wb23.x;
    den[3] += (float)wb23.y;
  }

#pragma unroll
  for (int k = 0; k < 8; ++k) acc[k] += __shfl_xor(acc[k], 32, 64);
#pragma unroll
  for (int k = 0; k < 4; ++k) den[k] += __shfl_xor(den[k], 32, 64);

  if (lane < 32) {
    float i0 = 1.f / (den[0] + 1e-30f);
    float i1 = 1.f / (den[1] + 1e-30f);
    float i2 = 1.f / (den[2] + 1e-30f);
    float i3 = 1.f / (den[3] + 1e-30f);
    float2 b2 = *reinterpret_cast<const float2*>(bias + 2 * lane);
    float rA = 0.25f * (acc[0] * i0 + acc[1] * i1 + acc[2] * i2 + acc[3] * i3) + b2.x;
    float rB = 0.25f * (acc[4] * i0 + acc[5] * i1 + acc[6] * i2 + acc[7] * i3) + b2.y;
    *reinterpret_cast<float2*>(out + (size_t)n * CH + 2 * lane) = make_float2(rA, rB);
  }
}

extern "C" void kernel_launch(void* const* d_in, const int* in_sizes, int n_in,
                              void* d_out, int out_size, void* d_ws, size_t ws_size,
                              hipStream_t stream) {
  const float* x       = (const float*)d_in[0];
  const int*   eidx    = (const int*)d_in[1];
  const float* W       = (const float*)d_in[2];
  const float* att_src = (const float*)d_in[3];
  const float* att_dst = (const float*)d_in[4];
  const float* bias    = (const float*)d_in[5];
  float* out = (float*)d_out;

  uint2* Hmp    = (uint2*)d_ws;                               // N*64 uint2 (51.2MB)
  uint4* erec   = (uint4*)(Hmp + (size_t)N_NODES * 64);       // TOT uint4 (27.2MB)
  float* as_buf = (float*)(erec + (size_t)TOT + 8);           // N*4
  float* ad_buf = as_buf + (size_t)N_NODES * NHEAD;           // N*4
  uint4* Wt_arr = (uint4*)(ad_buf + (size_t)N_NODES * NHEAD); // 8192 uint4 (128KB)
  int*   deg    = (int*)(Wt_arr + 8192);                      // N (reused as cursor)
  int*   rp     = deg + N_NODES;                              // N+1
  int*   bsum   = rp + N_NODES + 1;                           // 128
  int*   boff   = bsum + 128;                                 // 128

  const int* esrc = eidx;
  const int* edst = eidx + N_EDGES;

  conv_w<<<32, 256, 0, stream>>>(W, Wt_arr);
  hipMemsetAsync(deg, 0, (size_t)N_NODES * sizeof(int), stream);
  count_deg<<<(N_EDGES / 4 + 255) / 256, 256, 0, stream>>>(edst, deg);

  dim3 ggrid((N_NODES + 63) / 64);  // 1563 blocks x 256 threads
  gemm_mfma<<<ggrid, 256, 0, stream>>>(x, Wt_arr, att_src, att_dst, Hmp, as_buf, ad_buf,
                                       N_NODES);

  scan1<<<NBLK1, 256, 0, stream>>>(deg, rp, bsum);
  scan2<<<1, 128, 0, stream>>>(bsum, boff);
  scan3<<<(N_NODES + 255) / 256, 256, 0, stream>>>(rp, boff, deg /*cursor*/);
  scatter_edges<<<(TOT + 255) / 256, 256, 0, stream>>>(esrc, edst, as_buf, ad_buf,
                                                       deg /*cursor*/, erec);

  aggregate<<<(N_NODES + 3) / 4, 256, 0, stream>>>(rp, erec, Hmp, bias, out);
}

// Round 14
// 316.046 us; speedup vs baseline: 1.0602x; 1.0400x over previous
//
#include <hip/hip_runtime.h>

#define N_NODES 100000
#define N_EDGES 1600000
#define TOT (N_EDGES + N_NODES)
#define IN_CH 256
#define NHEAD 4
#define CH 64
#define HC 256
#define NEG_SLOPE 0.2f
#define DEG_BLOCKS 391  // 391*256*4 int4 >= 400,000

typedef _Float16 half8 __attribute__((ext_vector_type(8)));
typedef _Float16 h2v __attribute__((ext_vector_type(2)));
typedef float f32x4 __attribute__((ext_vector_type(4)));
typedef unsigned short ushort_t;
typedef unsigned int uint_t;

static __device__ __forceinline__ ushort_t f2h(float f) {
  _Float16 h = (_Float16)f;
  return __builtin_bit_cast(ushort_t, h);
}

// async global->LDS, 16B per lane (dest = wave-uniform base + lane*16)
static __device__ __forceinline__ void gload_lds16(const char* g, char* l) {
  __builtin_amdgcn_global_load_lds(
      (const __attribute__((address_space(1))) unsigned int*)g,
      (__attribute__((address_space(3))) unsigned int*)l, 16, 0, 0);
}

// ---------------- W fp32 [K=256][N=256] -> Wt_arr, MFMA-fragment-major ----------------
__global__ __launch_bounds__(256) void conv_w(const float* __restrict__ W,
                                              uint4* __restrict__ Wt_arr) {
  int id = blockIdx.x * 256 + threadIdx.x;  // 0..8191
  int lane = id & 63;
  int n = (id >> 6) & 15;
  int ks = id >> 10;
  int col = n * 16 + (lane & 15);
  int kbase = ks * 32 + (lane >> 4) * 8;
  ushort_t h[8];
#pragma unroll
  for (int j = 0; j < 8; ++j) h[j] = f2h(W[(size_t)(kbase + j) * HC + col]);
  uint4 u;
  u.x = (uint_t)h[0] | ((uint_t)h[1] << 16);
  u.y = (uint_t)h[2] | ((uint_t)h[3] << 16);
  u.z = (uint_t)h[4] | ((uint_t)h[5] << 16);
  u.w = (uint_t)h[6] | ((uint_t)h[7] << 16);
  Wt_arr[id] = u;
}

// ---------------- grid-mix: deg-count blocks + MFMA GEMM blocks ----------------
// Blocks [0, DEG_BLOCKS): degree histogram (4 int4/thread), early return.
// Blocks [DEG_BLOCKS, ...): R13 coalesced-DMA double-buffered GEMM (unchanged).
__global__ __launch_bounds__(256) void gemm_mfma(const float* __restrict__ X,
                                                 const uint4* __restrict__ Wt_arr,
                                                 const float* __restrict__ att_src,
                                                 const float* __restrict__ att_dst,
                                                 uint2* __restrict__ Hmp,
                                                 float* __restrict__ as_out,
                                                 float* __restrict__ ad_out,
                                                 const int* __restrict__ edst,
                                                 int* __restrict__ deg, int M) {
  const int tid = threadIdx.x;

  if (blockIdx.x < DEG_BLOCKS) {  // whole block: degree counting, no LDS/barriers
#pragma unroll
    for (int i = 0; i < 4; ++i) {
      int t = (blockIdx.x * 4 + i) * 256 + tid;
      if (t < N_EDGES / 4) {
        int4 d4 = reinterpret_cast<const int4*>(edst)[t];
        atomicAdd(&deg[d4.x], 1);
        atomicAdd(&deg[d4.y], 1);
        atomicAdd(&deg[d4.z], 1);
        atomicAdd(&deg[d4.w], 1);
      }
    }
    return;
  }

  __shared__ uint4 Bs[2][1024];                // 2 x 16 KB
  __shared__ __align__(16) float As[2][2048];  // 2 x 8 KB (64 rows x 32 f32)
  const int lane = tid & 63;
  const int wid = tid >> 6;
  const int l16 = lane & 15;
  const int lhi = lane >> 4;
  const int row0 = (blockIdx.x - DEG_BLOCKS) * 64;

  // A-DMA: linear dest; source slot XOR-swizzled (T2 via pre-swizzled global src)
  const int arow = tid >> 3;
  const int aslot = tid & 7;
  int ga0 = row0 + arow;       if (ga0 >= M) ga0 = M - 1;
  int ga1 = row0 + arow + 32;  if (ga1 >= M) ga1 = M - 1;
  const int sslot = aslot ^ (arow & 7);
  const char* asrc0 = (const char*)X + (size_t)ga0 * 1024 + (sslot << 4);
  const char* asrc1 = (const char*)X + (size_t)ga1 * 1024 + (sslot << 4);
  char* adst0 = (char*)&As[0][0] + tid * 16;
  char* adst1 = (char*)&As[1][0] + tid * 16;

  const char* __restrict__ wsrc = (const char*)Wt_arr;
  char* bd0 = (char*)&Bs[0][0] + tid * 16;
  char* bd1 = (char*)&Bs[1][0] + tid * 16;

  const int frow = wid * 16 + l16;
  const int sw = frow & 7;
  const int fo0 = frow * 32 + (((2 * lhi + 0) ^ sw) << 2);
  const int fo1 = frow * 32 + (((2 * lhi + 1) ^ sw) << 2);

  gload_lds16(asrc0, adst0);
  gload_lds16(asrc1, adst0 + 4096);
  gload_lds16(wsrc + tid * 16,         bd0);
  gload_lds16(wsrc + 4096 + tid * 16,  bd0 + 4096);
  gload_lds16(wsrc + 8192 + tid * 16,  bd0 + 8192);
  gload_lds16(wsrc + 12288 + tid * 16, bd0 + 12288);

  f32x4 acc[16] = {};
  int cur = 0;

#pragma unroll
  for (int ks = 0; ks < 8; ++ks) {
    __syncthreads();

    if (ks < 7) {
      char* ad = (cur == 0) ? adst1 : adst0;
      gload_lds16(asrc0 + (ks + 1) * 128, ad);
      gload_lds16(asrc1 + (ks + 1) * 128, ad + 4096);
      char* bd = (cur == 0) ? bd1 : bd0;
      const char* s = wsrc + (ks + 1) * 16384 + tid * 16;
      gload_lds16(s,         bd);
      gload_lds16(s + 4096,  bd + 4096);
      gload_lds16(s + 8192,  bd + 8192);
      gload_lds16(s + 12288, bd + 12288);
    }

    const float* Ab = &As[cur][0];
    float4 f0 = *reinterpret_cast<const float4*>(Ab + fo0);
    float4 f1 = *reinterpret_cast<const float4*>(Ab + fo1);
    uint4 ua;
    ua.x = __builtin_bit_cast(uint_t, __builtin_amdgcn_cvt_pkrtz(f0.x, f0.y));
    ua.y = __builtin_bit_cast(uint_t, __builtin_amdgcn_cvt_pkrtz(f0.z, f0.w));
    ua.z = __builtin_bit_cast(uint_t, __builtin_amdgcn_cvt_pkrtz(f1.x, f1.y));
    ua.w = __builtin_bit_cast(uint_t, __builtin_amdgcn_cvt_pkrtz(f1.z, f1.w));
    half8 a = __builtin_bit_cast(half8, ua);

    const char* bbase = (const char*)&Bs[cur][0];
#pragma unroll
    for (int n = 0; n < 16; ++n) {
      half8 b = *reinterpret_cast<const half8*>(bbase + n * 1024 + lane * 16);
      acc[n] = __builtin_amdgcn_mfma_f32_16x16x32_f16(a, b, acc[n], 0, 0, 0);
    }
    cur ^= 1;
  }

  float attS[16], attD[16];
#pragma unroll
  for (int n = 0; n < 16; ++n) {
    attS[n] = att_src[n * 16 + l16];
    attD[n] = att_dst[n * 16 + l16];
  }

#pragma unroll
  for (int r = 0; r < 4; ++r) {
    int grow = row0 + wid * 16 + lhi * 4 + r;
    if (grow < M) {
#pragma unroll
      for (int n2 = 0; n2 < 4; ++n2) {
        uint_t pk01 = __builtin_bit_cast(uint_t,
            __builtin_amdgcn_cvt_pkrtz(acc[n2][r], acc[n2 + 4][r]));
        uint_t pk23 = __builtin_bit_cast(uint_t,
            __builtin_amdgcn_cvt_pkrtz(acc[n2 + 8][r], acc[n2 + 12][r]));
        Hmp[(size_t)grow * 64 + n2 * 16 + l16] = make_uint2(pk01, pk23);
      }
      float sv[4] = {0.f, 0.f, 0.f, 0.f}, dv[4] = {0.f, 0.f, 0.f, 0.f};
#pragma unroll
      for (int h = 0; h < 4; ++h)
#pragma unroll
        for (int j = 0; j < 4; ++j) {
          sv[h] += acc[h * 4 + j][r] * attS[h * 4 + j];
          dv[h] += acc[h * 4 + j][r] * attD[h * 4 + j];
        }
#pragma unroll
      for (int off = 1; off < 16; off <<= 1)
#pragma unroll
        for (int h = 0; h < 4; ++h) {
          sv[h] += __shfl_xor(sv[h], off, 16);
          dv[h] += __shfl_xor(dv[h], off, 16);
        }
      if (l16 == 0) {
#pragma unroll
        for (int h = 0; h < 4; ++h) {
          as_out[(size_t)grow * 4 + h] = sv[h];
          ad_out[(size_t)grow * 4 + h] = dv[h];
        }
      }
    }
  }
}

// ---------------- CSR build (scan1 adds +1 self-loop inline) ----------------
__global__ __launch_bounds__(256) void scan1(const int* __restrict__ deg,
                                             int* __restrict__ rp,
                                             int* __restrict__ bsum) {
  __shared__ int sh[256];
  int t = threadIdx.x;
  int base = blockIdx.x * 1024 + t * 4;
  int v[4];
#pragma unroll
  for (int i = 0; i < 4; ++i) v[i] = (base + i < N_NODES) ? (deg[base + i] + 1) : 0;
  int tsum = v[0] + v[1] + v[2] + v[3];
  sh[t] = tsum;
  __syncthreads();
  for (int off = 1; off < 256; off <<= 1) {
    int x = (t >= off) ? sh[t - off] : 0;
    __syncthreads();
    sh[t] += x;
    __syncthreads();
  }
  if (t == 255) bsum[blockIdx.x] = sh[255];
  int run = sh[t] - tsum;
#pragma unroll
  for (int i = 0; i < 4; ++i) {
    if (base + i < N_NODES) rp[base + i] = run;
    run += v[i];
  }
}

#define NBLK1 ((N_NODES + 1023) / 1024)  // 98

__global__ __launch_bounds__(128) void scan2(const int* __restrict__ bsum,
                                             int* __restrict__ boff) {
  __shared__ int sh[128];
  int t = threadIdx.x;
  int own = (t < NBLK1) ? bsum[t] : 0;
  sh[t] = own;
  __syncthreads();
  for (int off = 1; off < 128; off <<= 1) {
    int x = (t >= off) ? sh[t - off] : 0;
    __syncthreads();
    sh[t] += x;
    __syncthreads();
  }
  boff[t] = sh[t] - own;
}

__global__ __launch_bounds__(256) void scan3(int* __restrict__ rp,
                                             const int* __restrict__ boff,
                                             int* __restrict__ cursor) {
  int idx = blockIdx.x * 256 + threadIdx.x;
  if (idx < N_NODES) {
    int v = rp[idx] + boff[idx >> 10];
    rp[idx] = v;
    cursor[idx] = v;
  }
  if (idx == 0) rp[N_NODES] = TOT;
}

// scatter + fused edge-weight computation -> one 16B record {src, w01, w23, 0}
__global__ __launch_bounds__(256) void scatter_edges(const int* __restrict__ esrc,
                                                     const int* __restrict__ edst,
                                                     const float* __restrict__ as_buf,
                                                     const float* __restrict__ ad_buf,
                                                     int* __restrict__ cursor,
                                                     uint4* __restrict__ erec) {
  int e = blockIdx.x * 256 + threadIdx.x;
  if (e >= TOT) return;
  int s, d;
  if (e < N_EDGES) { s = esrc[e]; d = edst[e]; }
  else { s = e - N_EDGES; d = s; }
  int p = atomicAdd(&cursor[d], 1);
  float4 a1 = *reinterpret_cast<const float4*>(as_buf + (size_t)s * NHEAD);
  float4 a2 = *reinterpret_cast<const float4*>(ad_buf + (size_t)d * NHEAD);
  float e0 = a1.x + a2.x; e0 = e0 > 0.f ? e0 : NEG_SLOPE * e0;
  float e1 = a1.y + a2.y; e1 = e1 > 0.f ? e1 : NEG_SLOPE * e1;
  float e2 = a1.z + a2.z; e2 = e2 > 0.f ? e2 : NEG_SLOPE * e2;
  float e3 = a1.w + a2.w; e3 = e3 > 0.f ? e3 : NEG_SLOPE * e3;
  float w0 = __expf(e0 - 4.f), w1 = __expf(e1 - 4.f);
  float w2 = __expf(e2 - 4.f), w3 = __expf(e3 - 4.f);
  uint_t pk01 = __builtin_bit_cast(uint_t, __builtin_amdgcn_cvt_pkrtz(w0, w1));
  uint_t pk23 = __builtin_bit_cast(uint_t, __builtin_amdgcn_cvt_pkrtz(w2, w3));
  erec[p] = make_uint4((uint_t)s, pk01, pk23, 0u);
}

// ---------------- fused softmax + aggregation: 8 edges/iter ----------------
// One wave per node; 4 records per lane in flight (half-wave per edge).
static __device__ __forceinline__ void accum_edge(uint4 cur, uint4 hv, bool act,
                                                  float* acc, float* den) {
  uint_t w01u = act ? cur.y : 0u;
  uint_t w23u = act ? cur.z : 0u;
  h2v w01 = __builtin_bit_cast(h2v, w01u);
  h2v w23 = __builtin_bit_cast(h2v, w23u);
  h2v ha = __builtin_bit_cast(h2v, hv.x);
  h2v hb = __builtin_bit_cast(h2v, hv.y);
  h2v hc = __builtin_bit_cast(h2v, hv.z);
  h2v hd = __builtin_bit_cast(h2v, hv.w);
  acc[0] += (float)w01.x * (float)ha.x;
  acc[1] += (float)w01.y * (float)ha.y;
  acc[2] += (float)w23.x * (float)hb.x;
  acc[3] += (float)w23.y * (float)hb.y;
  acc[4] += (float)w01.x * (float)hc.x;
  acc[5] += (float)w01.y * (float)hc.y;
  acc[6] += (float)w23.x * (float)hd.x;
  acc[7] += (float)w23.y * (float)hd.y;
  den[0] += (float)w01.x;
  den[1] += (float)w01.y;
  den[2] += (float)w23.x;
  den[3] += (float)w23.y;
}

__global__ __launch_bounds__(256) void aggregate(const int* __restrict__ rp,
                                                 const uint4* __restrict__ erec,
                                                 const uint2* __restrict__ Hp,
                                                 const float* __restrict__ bias,
                                                 float* __restrict__ out) {
  int n = blockIdx.x * 4 + (threadIdx.x >> 6);
  int lane = threadIdx.x & 63;
  if (n >= N_NODES) return;
  const int half = lane >> 5;
  const uint_t off_lane = (uint_t)(lane & 31) << 4;
  const char* __restrict__ Hb = (const char*)Hp;

  int beg = rp[n], end = rp[n + 1];
  const int last = end - 1;

  float acc[8] = {};
  float den[4] = {};

  int i0 = beg + half;     if (i0 > last) i0 = last;
  int i1 = beg + 2 + half; if (i1 > last) i1 = last;
  int i2 = beg + 4 + half; if (i2 > last) i2 = last;
  int i3 = beg + 6 + half; if (i3 > last) i3 = last;
  uint4 r0 = erec[i0], r1 = erec[i1], r2 = erec[i2], r3 = erec[i3];

  for (int j = beg; j < end; j += 8) {
    uint4 c0 = r0, c1 = r1, c2 = r2, c3 = r3;
    i0 = j + 8 + half;  if (i0 > last) i0 = last;
    i1 = j + 10 + half; if (i1 > last) i1 = last;
    i2 = j + 12 + half; if (i2 > last) i2 = last;
    i3 = j + 14 + half; if (i3 > last) i3 = last;
    r0 = erec[i0]; r1 = erec[i1]; r2 = erec[i2]; r3 = erec[i3];

    // issue all 4 gathers before consuming any
    uint4 h0 = *reinterpret_cast<const uint4*>(Hb + ((c0.x << 9) | off_lane));
    uint4 h1 = *reinterpret_cast<const uint4*>(Hb + ((c1.x << 9) | off_lane));
    uint4 h2 = *reinterpret_cast<const uint4*>(Hb + ((c2.x << 9) | off_lane));
    uint4 h3 = *reinterpret_cast<const uint4*>(Hb + ((c3.x << 9) | off_lane));

    accum_edge(c0, h0, (j + half) < end, acc, den);
    accum_edge(c1, h1, (j + 2 + half) < end, acc, den);
    accum_edge(c2, h2, (j + 4 + half) < end, acc, den);
    accum_edge(c3, h3, (j + 6 + half) < end, acc, den);
  }

#pragma unroll
  for (int k = 0; k < 8; ++k) acc[k] += __shfl_xor(acc[k], 32, 64);
#pragma unroll
  for (int k = 0; k < 4; ++k) den[k] += __shfl_xor(den[k], 32, 64);

  if (lane < 32) {
    float i0v = 1.f / (den[0] + 1e-30f);
    float i1v = 1.f / (den[1] + 1e-30f);
    float i2v = 1.f / (den[2] + 1e-30f);
    float i3v = 1.f / (den[3] + 1e-30f);
    float2 b2 = *reinterpret_cast<const float2*>(bias + 2 * lane);
    float rA = 0.25f * (acc[0] * i0v + acc[1] * i1v + acc[2] * i2v + acc[3] * i3v) + b2.x;
    float rB = 0.25f * (acc[4] * i0v + acc[5] * i1v + acc[6] * i2v + acc[7] * i3v) + b2.y;
    *reinterpret_cast<float2*>(out + (size_t)n * CH + 2 * lane) = make_float2(rA, rB);
  }
}

extern "C" void kernel_launch(void* const* d_in, const int* in_sizes, int n_in,
                              void* d_out, int out_size, void* d_ws, size_t ws_size,
                              hipStream_t stream) {
  const float* x       = (const float*)d_in[0];
  const int*   eidx    = (const int*)d_in[1];
  const float* W       = (const float*)d_in[2];
  const float* att_src = (const float*)d_in[3];
  const float* att_dst = (const float*)d_in[4];
  const float* bias    = (const float*)d_in[5];
  float* out = (float*)d_out;

  uint2* Hmp    = (uint2*)d_ws;                               // N*64 uint2 (51.2MB)
  uint4* erec   = (uint4*)(Hmp + (size_t)N_NODES * 64);       // TOT uint4 (27.2MB)
  float* as_buf = (float*)(erec + (size_t)TOT + 8);           // N*4
  float* ad_buf = as_buf + (size_t)N_NODES * NHEAD;           // N*4
  uint4* Wt_arr = (uint4*)(ad_buf + (size_t)N_NODES * NHEAD); // 8192 uint4 (128KB)
  int*   deg    = (int*)(Wt_arr + 8192);                      // N (reused as cursor)
  int*   rp     = deg + N_NODES;                              // N+1
  int*   bsum   = rp + N_NODES + 1;                           // 128
  int*   boff   = bsum + 128;                                 // 128

  const int* esrc = eidx;
  const int* edst = eidx + N_EDGES;

  conv_w<<<32, 256, 0, stream>>>(W, Wt_arr);
  hipMemsetAsync(deg, 0, (size_t)N_NODES * sizeof(int), stream);

  // grid-mix: 391 deg-count blocks + 1563 GEMM blocks in one dispatch
  dim3 ggrid(DEG_BLOCKS + (N_NODES + 63) / 64);
  gemm_mfma<<<ggrid, 256, 0, stream>>>(x, Wt_arr, att_src, att_dst, Hmp, as_buf, ad_buf,
                                       edst, deg, N_NODES);

  scan1<<<NBLK1, 256, 0, stream>>>(deg, rp, bsum);
  scan2<<<1, 128, 0, stream>>>(bsum, boff);
  scan3<<<(N_NODES + 255) / 256, 256, 0, stream>>>(rp, boff, deg /*cursor*/);
  scatter_edges<<<(TOT + 255) / 256, 256, 0, stream>>>(esrc, edst, as_buf, ad_buf,
                                                       deg /*cursor*/, erec);

  aggregate<<<(N_NODES + 3) / 4, 256, 0, stream>>>(rp, erec, Hmp, bias, out);
}

// Round 15
// 310.388 us; speedup vs baseline: 1.0795x; 1.0182x over previous
//
#include <hip/hip_runtime.h>

#define N_NODES 100000
#define N_EDGES 1600000
#define TOT (N_EDGES + N_NODES)
#define IN_CH 256
#define NHEAD 4
#define CH 64
#define HC 256
#define NEG_SLOPE 0.2f
#define DEG_BLOCKS 391  // 391*256*4 int4 >= 400,000

typedef _Float16 half8 __attribute__((ext_vector_type(8)));
typedef _Float16 h2v __attribute__((ext_vector_type(2)));
typedef float f32x4 __attribute__((ext_vector_type(4)));
typedef unsigned short ushort_t;
typedef unsigned int uint_t;

static __device__ __forceinline__ ushort_t f2h(float f) {
  _Float16 h = (_Float16)f;
  return __builtin_bit_cast(ushort_t, h);
}

// async global->LDS, 16B per lane (dest = wave-uniform base + lane*16)
static __device__ __forceinline__ void gload_lds16(const char* g, char* l) {
  __builtin_amdgcn_global_load_lds(
      (const __attribute__((address_space(1))) unsigned int*)g,
      (__attribute__((address_space(3))) unsigned int*)l, 16, 0, 0);
}

// ---------------- W fp32 [K=256][N=256] -> Wt_arr, MFMA-fragment-major ----------------
__global__ __launch_bounds__(256) void conv_w(const float* __restrict__ W,
                                              uint4* __restrict__ Wt_arr) {
  int id = blockIdx.x * 256 + threadIdx.x;  // 0..8191
  int lane = id & 63;
  int n = (id >> 6) & 15;
  int ks = id >> 10;
  int col = n * 16 + (lane & 15);
  int kbase = ks * 32 + (lane >> 4) * 8;
  ushort_t h[8];
#pragma unroll
  for (int j = 0; j < 8; ++j) h[j] = f2h(W[(size_t)(kbase + j) * HC + col]);
  uint4 u;
  u.x = (uint_t)h[0] | ((uint_t)h[1] << 16);
  u.y = (uint_t)h[2] | ((uint_t)h[3] << 16);
  u.z = (uint_t)h[4] | ((uint_t)h[5] << 16);
  u.w = (uint_t)h[6] | ((uint_t)h[7] << 16);
  Wt_arr[id] = u;
}

// ---------------- grid-mix: deg-count blocks + MFMA GEMM (T3/T4 pipeline) ------------
// GEMM: triple-buffered LDS staging, RAW s_barrier + counted vmcnt (never 0 in loop):
// batches for steps ks+1, ks+2 stay in flight across each barrier.
__global__ __launch_bounds__(256) void gemm_mfma(const float* __restrict__ X,
                                                 const uint4* __restrict__ Wt_arr,
                                                 const float* __restrict__ att_src,
                                                 const float* __restrict__ att_dst,
                                                 uint2* __restrict__ Hmp,
                                                 float* __restrict__ as_out,
                                                 float* __restrict__ ad_out,
                                                 const int* __restrict__ edst,
                                                 int* __restrict__ deg, int M) {
  const int tid = threadIdx.x;

  if (blockIdx.x < DEG_BLOCKS) {  // degree-count blocks: no LDS, no barriers
#pragma unroll
    for (int i = 0; i < 4; ++i) {
      int t = (blockIdx.x * 4 + i) * 256 + tid;
      if (t < N_EDGES / 4) {
        int4 d4 = reinterpret_cast<const int4*>(edst)[t];
        atomicAdd(&deg[d4.x], 1);
        atomicAdd(&deg[d4.y], 1);
        atomicAdd(&deg[d4.z], 1);
        atomicAdd(&deg[d4.w], 1);
      }
    }
    return;
  }

  __shared__ uint4 Bs[3][1024];                // 3 x 16 KB
  __shared__ __align__(16) float As[3][2048];  // 3 x 8 KB (64 rows x 32 f32)
  const int lane = tid & 63;
  const int wid = tid >> 6;
  const int l16 = lane & 15;
  const int lhi = lane >> 4;
  const int row0 = (blockIdx.x - DEG_BLOCKS) * 64;

  // A-DMA: linear dest; source slot XOR-swizzled (T2 via pre-swizzled global src)
  const int arow = tid >> 3;
  const int aslot = tid & 7;
  int ga0 = row0 + arow;       if (ga0 >= M) ga0 = M - 1;
  int ga1 = row0 + arow + 32;  if (ga1 >= M) ga1 = M - 1;
  const int sslot = aslot ^ (arow & 7);
  const char* asrc0 = (const char*)X + (size_t)ga0 * 1024 + (sslot << 4);
  const char* asrc1 = (const char*)X + (size_t)ga1 * 1024 + (sslot << 4);

  const char* __restrict__ wsrc = (const char*)Wt_arr;

  // fragment read geometry (XOR-swizzled)
  const int frow = wid * 16 + l16;
  const int sw = frow & 7;
  const int fo0 = frow * 32 + (((2 * lhi + 0) ^ sw) << 2);
  const int fo1 = frow * 32 + (((2 * lhi + 1) ^ sw) << 2);

  // stage batch kk into buffer b (6 DMA ops per thread = one vmcnt batch)
  auto ISSUE = [&](int kk, int b) {
    char* ad = (char*)&As[b][0] + tid * 16;
    gload_lds16(asrc0 + kk * 128, ad);
    gload_lds16(asrc1 + kk * 128, ad + 4096);
    char* bd = (char*)&Bs[b][0] + tid * 16;
    const char* s = wsrc + kk * 16384 + tid * 16;
    gload_lds16(s,         bd);
    gload_lds16(s + 4096,  bd + 4096);
    gload_lds16(s + 8192,  bd + 8192);
    gload_lds16(s + 12288, bd + 12288);
  };

  // prologue: two batches in flight
  ISSUE(0, 0);
  ISSUE(1, 1);

  f32x4 acc[16] = {};

#pragma unroll
  for (int ks = 0; ks < 8; ++ks) {
    // raw barrier: ensures all waves finished reading buf[(ks-1)%3] == buf[(ks+2)%3].
    // Does NOT drain vmcnt - batches ks, ks+1 stay in flight across it.
    __builtin_amdgcn_s_barrier();
    if (ks < 6) ISSUE(ks + 2, (ks + 2) % 3);
    // counted wait: oldest batch (ks) complete; newer batches remain outstanding.
    if (ks < 6)      asm volatile("s_waitcnt vmcnt(12)" ::: "memory");
    else if (ks == 6) asm volatile("s_waitcnt vmcnt(6)" ::: "memory");
    else              asm volatile("s_waitcnt vmcnt(0)" ::: "memory");

    const float* Ab = &As[ks % 3][0];
    float4 f0 = *reinterpret_cast<const float4*>(Ab + fo0);
    float4 f1 = *reinterpret_cast<const float4*>(Ab + fo1);
    uint4 ua;
    ua.x = __builtin_bit_cast(uint_t, __builtin_amdgcn_cvt_pkrtz(f0.x, f0.y));
    ua.y = __builtin_bit_cast(uint_t, __builtin_amdgcn_cvt_pkrtz(f0.z, f0.w));
    ua.z = __builtin_bit_cast(uint_t, __builtin_amdgcn_cvt_pkrtz(f1.x, f1.y));
    ua.w = __builtin_bit_cast(uint_t, __builtin_amdgcn_cvt_pkrtz(f1.z, f1.w));
    half8 a = __builtin_bit_cast(half8, ua);

    const char* bbase = (const char*)&Bs[ks % 3][0];
#pragma unroll
    for (int n = 0; n < 16; ++n) {
      half8 b = *reinterpret_cast<const half8*>(bbase + n * 1024 + lane * 16);
      acc[n] = __builtin_amdgcn_mfma_f32_16x16x32_f16(a, b, acc[n], 0, 0, 0);
    }
  }

  // epilogue: pack Hmp + fused attention dots
  float attS[16], attD[16];
#pragma unroll
  for (int n = 0; n < 16; ++n) {
    attS[n] = att_src[n * 16 + l16];
    attD[n] = att_dst[n * 16 + l16];
  }

#pragma unroll
  for (int r = 0; r < 4; ++r) {
    int grow = row0 + wid * 16 + lhi * 4 + r;
    if (grow < M) {
#pragma unroll
      for (int n2 = 0; n2 < 4; ++n2) {
        uint_t pk01 = __builtin_bit_cast(uint_t,
            __builtin_amdgcn_cvt_pkrtz(acc[n2][r], acc[n2 + 4][r]));
        uint_t pk23 = __builtin_bit_cast(uint_t,
            __builtin_amdgcn_cvt_pkrtz(acc[n2 + 8][r], acc[n2 + 12][r]));
        Hmp[(size_t)grow * 64 + n2 * 16 + l16] = make_uint2(pk01, pk23);
      }
      float sv[4] = {0.f, 0.f, 0.f, 0.f}, dv[4] = {0.f, 0.f, 0.f, 0.f};
#pragma unroll
      for (int h = 0; h < 4; ++h)
#pragma unroll
        for (int j = 0; j < 4; ++j) {
          sv[h] += acc[h * 4 + j][r] * attS[h * 4 + j];
          dv[h] += acc[h * 4 + j][r] * attD[h * 4 + j];
        }
#pragma unroll
      for (int off = 1; off < 16; off <<= 1)
#pragma unroll
        for (int h = 0; h < 4; ++h) {
          sv[h] += __shfl_xor(sv[h], off, 16);
          dv[h] += __shfl_xor(dv[h], off, 16);
        }
      if (l16 == 0) {
#pragma unroll
        for (int h = 0; h < 4; ++h) {
          as_out[(size_t)grow * 4 + h] = sv[h];
          ad_out[(size_t)grow * 4 + h] = dv[h];
        }
      }
    }
  }
}

// ---------------- CSR build (scan1 adds +1 self-loop inline) ----------------
__global__ __launch_bounds__(256) void scan1(const int* __restrict__ deg,
                                             int* __restrict__ rp,
                                             int* __restrict__ bsum) {
  __shared__ int sh[256];
  int t = threadIdx.x;
  int base = blockIdx.x * 1024 + t * 4;
  int v[4];
#pragma unroll
  for (int i = 0; i < 4; ++i) v[i] = (base + i < N_NODES) ? (deg[base + i] + 1) : 0;
  int tsum = v[0] + v[1] + v[2] + v[3];
  sh[t] = tsum;
  __syncthreads();
  for (int off = 1; off < 256; off <<= 1) {
    int x = (t >= off) ? sh[t - off] : 0;
    __syncthreads();
    sh[t] += x;
    __syncthreads();
  }
  if (t == 255) bsum[blockIdx.x] = sh[255];
  int run = sh[t] - tsum;
#pragma unroll
  for (int i = 0; i < 4; ++i) {
    if (base + i < N_NODES) rp[base + i] = run;
    run += v[i];
  }
}

#define NBLK1 ((N_NODES + 1023) / 1024)  // 98

__global__ __launch_bounds__(128) void scan2(const int* __restrict__ bsum,
                                             int* __restrict__ boff) {
  __shared__ int sh[128];
  int t = threadIdx.x;
  int own = (t < NBLK1) ? bsum[t] : 0;
  sh[t] = own;
  __syncthreads();
  for (int off = 1; off < 128; off <<= 1) {
    int x = (t >= off) ? sh[t - off] : 0;
    __syncthreads();
    sh[t] += x;
    __syncthreads();
  }
  boff[t] = sh[t] - own;
}

__global__ __launch_bounds__(256) void scan3(int* __restrict__ rp,
                                             const int* __restrict__ boff,
                                             int* __restrict__ cursor) {
  int idx = blockIdx.x * 256 + threadIdx.x;
  if (idx < N_NODES) {
    int v = rp[idx] + boff[idx >> 10];
    rp[idx] = v;
    cursor[idx] = v;
  }
  if (idx == 0) rp[N_NODES] = TOT;
}

// scatter + fused edge-weight computation -> one 16B record {src, w01, w23, 0}
__global__ __launch_bounds__(256) void scatter_edges(const int* __restrict__ esrc,
                                                     const int* __restrict__ edst,
                                                     const float* __restrict__ as_buf,
                                                     const float* __restrict__ ad_buf,
                                                     int* __restrict__ cursor,
                                                     uint4* __restrict__ erec) {
  int e = blockIdx.x * 256 + threadIdx.x;
  if (e >= TOT) return;
  int s, d;
  if (e < N_EDGES) { s = esrc[e]; d = edst[e]; }
  else { s = e - N_EDGES; d = s; }
  int p = atomicAdd(&cursor[d], 1);
  float4 a1 = *reinterpret_cast<const float4*>(as_buf + (size_t)s * NHEAD);
  float4 a2 = *reinterpret_cast<const float4*>(ad_buf + (size_t)d * NHEAD);
  float e0 = a1.x + a2.x; e0 = e0 > 0.f ? e0 : NEG_SLOPE * e0;
  float e1 = a1.y + a2.y; e1 = e1 > 0.f ? e1 : NEG_SLOPE * e1;
  float e2 = a1.z + a2.z; e2 = e2 > 0.f ? e2 : NEG_SLOPE * e2;
  float e3 = a1.w + a2.w; e3 = e3 > 0.f ? e3 : NEG_SLOPE * e3;
  float w0 = __expf(e0 - 4.f), w1 = __expf(e1 - 4.f);
  float w2 = __expf(e2 - 4.f), w3 = __expf(e3 - 4.f);
  uint_t pk01 = __builtin_bit_cast(uint_t, __builtin_amdgcn_cvt_pkrtz(w0, w1));
  uint_t pk23 = __builtin_bit_cast(uint_t, __builtin_amdgcn_cvt_pkrtz(w2, w3));
  erec[p] = make_uint4((uint_t)s, pk01, pk23, 0u);
}

// ---------------- fused softmax + aggregation: 8 edges/iter ----------------
static __device__ __forceinline__ void accum_edge(uint4 cur, uint4 hv, bool act,
                                                  float* acc, float* den) {
  uint_t w01u = act ? cur.y : 0u;
  uint_t w23u = act ? cur.z : 0u;
  h2v w01 = __builtin_bit_cast(h2v, w01u);
  h2v w23 = __builtin_bit_cast(h2v, w23u);
  h2v ha = __builtin_bit_cast(h2v, hv.x);
  h2v hb = __builtin_bit_cast(h2v, hv.y);
  h2v hc = __builtin_bit_cast(h2v, hv.z);
  h2v hd = __builtin_bit_cast(h2v, hv.w);
  acc[0] += (float)w01.x * (float)ha.x;
  acc[1] += (float)w01.y * (float)ha.y;
  acc[2] += (float)w23.x * (float)hb.x;
  acc[3] += (float)w23.y * (float)hb.y;
  acc[4] += (float)w01.x * (float)hc.x;
  acc[5] += (float)w01.y * (float)hc.y;
  acc[6] += (float)w23.x * (float)hd.x;
  acc[7] += (float)w23.y * (float)hd.y;
  den[0] += (float)w01.x;
  den[1] += (float)w01.y;
  den[2] += (float)w23.x;
  den[3] += (float)w23.y;
}

__global__ __launch_bounds__(256) void aggregate(const int* __restrict__ rp,
                                                 const uint4* __restrict__ erec,
                                                 const uint2* __restrict__ Hp,
                                                 const float* __restrict__ bias,
                                                 float* __restrict__ out) {
  int n = blockIdx.x * 4 + (threadIdx.x >> 6);
  int lane = threadIdx.x & 63;
  if (n >= N_NODES) return;
  const int half = lane >> 5;
  const uint_t off_lane = (uint_t)(lane & 31) << 4;
  const char* __restrict__ Hb = (const char*)Hp;

  int beg = rp[n], end = rp[n + 1];
  const int last = end - 1;

  float acc[8] = {};
  float den[4] = {};

  int i0 = beg + half;     if (i0 > last) i0 = last;
  int i1 = beg + 2 + half; if (i1 > last) i1 = last;
  int i2 = beg + 4 + half; if (i2 > last) i2 = last;
  int i3 = beg + 6 + half; if (i3 > last) i3 = last;
  uint4 r0 = erec[i0], r1 = erec[i1], r2 = erec[i2], r3 = erec[i3];

  for (int j = beg; j < end; j += 8) {
    uint4 c0 = r0, c1 = r1, c2 = r2, c3 = r3;
    i0 = j + 8 + half;  if (i0 > last) i0 = last;
    i1 = j + 10 + half; if (i1 > last) i1 = last;
    i2 = j + 12 + half; if (i2 > last) i2 = last;
    i3 = j + 14 + half; if (i3 > last) i3 = last;
    r0 = erec[i0]; r1 = erec[i1]; r2 = erec[i2]; r3 = erec[i3];

    uint4 h0 = *reinterpret_cast<const uint4*>(Hb + ((c0.x << 9) | off_lane));
    uint4 h1 = *reinterpret_cast<const uint4*>(Hb + ((c1.x << 9) | off_lane));
    uint4 h2 = *reinterpret_cast<const uint4*>(Hb + ((c2.x << 9) | off_lane));
    uint4 h3 = *reinterpret_cast<const uint4*>(Hb + ((c3.x << 9) | off_lane));

    accum_edge(c0, h0, (j + half) < end, acc, den);
    accum_edge(c1, h1, (j + 2 + half) < end, acc, den);
    accum_edge(c2, h2, (j + 4 + half) < end, acc, den);
    accum_edge(c3, h3, (j + 6 + half) < end, acc, den);
  }

#pragma unroll
  for (int k = 0; k < 8; ++k) acc[k] += __shfl_xor(acc[k], 32, 64);
#pragma unroll
  for (int k = 0; k < 4; ++k) den[k] += __shfl_xor(den[k], 32, 64);

  if (lane < 32) {
    float i0v = 1.f / (den[0] + 1e-30f);
    float i1v = 1.f / (den[1] + 1e-30f);
    float i2v = 1.f / (den[2] + 1e-30f);
    float i3v = 1.f / (den[3] + 1e-30f);
    float2 b2 = *reinterpret_cast<const float2*>(bias + 2 * lane);
    float rA = 0.25f * (acc[0] * i0v + acc[1] * i1v + acc[2] * i2v + acc[3] * i3v) + b2.x;
    float rB = 0.25f * (acc[4] * i0v + acc[5] * i1v + acc[6] * i2v + acc[7] * i3v) + b2.y;
    *reinterpret_cast<float2*>(out + (size_t)n * CH + 2 * lane) = make_float2(rA, rB);
  }
}

extern "C" void kernel_launch(void* const* d_in, const int* in_sizes, int n_in,
                              void* d_out, int out_size, void* d_ws, size_t ws_size,
                              hipStream_t stream) {
  const float* x       = (const float*)d_in[0];
  const int*   eidx    = (const int*)d_in[1];
  const float* W       = (const float*)d_in[2];
  const float* att_src = (const float*)d_in[3];
  const float* att_dst = (const float*)d_in[4];
  const float* bias    = (const float*)d_in[5];
  float* out = (float*)d_out;

  uint2* Hmp    = (uint2*)d_ws;                               // N*64 uint2 (51.2MB)
  uint4* erec   = (uint4*)(Hmp + (size_t)N_NODES * 64);       // TOT uint4 (27.2MB)
  float* as_buf = (float*)(erec + (size_t)TOT + 8);           // N*4
  float* ad_buf = as_buf + (size_t)N_NODES * NHEAD;           // N*4
  uint4* Wt_arr = (uint4*)(ad_buf + (size_t)N_NODES * NHEAD); // 8192 uint4 (128KB)
  int*   deg    = (int*)(Wt_arr + 8192);                      // N (reused as cursor)
  int*   rp     = deg + N_NODES;                              // N+1
  int*   bsum   = rp + N_NODES + 1;                           // 128
  int*   boff   = bsum + 128;                                 // 128

  const int* esrc = eidx;
  const int* edst = eidx + N_EDGES;

  conv_w<<<32, 256, 0, stream>>>(W, Wt_arr);
  hipMemsetAsync(deg, 0, (size_t)N_NODES * sizeof(int), stream);

  // grid-mix: 391 deg-count blocks + 1563 GEMM blocks in one dispatch
  dim3 ggrid(DEG_BLOCKS + (N_NODES + 63) / 64);
  gemm_mfma<<<ggrid, 256, 0, stream>>>(x, Wt_arr, att_src, att_dst, Hmp, as_buf, ad_buf,
                                       edst, deg, N_NODES);

  scan1<<<NBLK1, 256, 0, stream>>>(deg, rp, bsum);
  scan2<<<1, 128, 0, stream>>>(bsum, boff);
  scan3<<<(N_NODES + 255) / 256, 256, 0, stream>>>(rp, boff, deg /*cursor*/);
  scatter_edges<<<(TOT + 255) / 256, 256, 0, stream>>>(esrc, edst, as_buf, ad_buf,
                                                       deg /*cursor*/, erec);

  aggregate<<<(N_NODES + 3) / 4, 256, 0, stream>>>(rp, erec, Hmp, bias, out);
}